// Round 5
// baseline (142.851 us; speedup 1.0000x reference)
//
#include <hip/hip_runtime.h>
#include <hip/hip_bf16.h>

typedef __bf16 bf16_t;
typedef __attribute__((ext_vector_type(4))) __bf16 bf16x4;
typedef __attribute__((ext_vector_type(8))) __bf16 bf16x8;
typedef __attribute__((ext_vector_type(4))) float f32x4;

#define B_ 8
#define T_ 2048
#define C_ 1024
#define H_ 64

// ---------------------------------------------------------------------------
// Kernel 1: convert + transpose weights -> Wt[w][h][k] bf16 (w: 0=q,1=k,2=v)
// ---------------------------------------------------------------------------
__global__ __launch_bounds__(256) void wprep_kernel(
    const float* __restrict__ Wq, const float* __restrict__ Wk,
    const float* __restrict__ Wv, bf16_t* __restrict__ Wt) {
  __shared__ float tile[64][68];
  const int t  = threadIdx.x;
  const int w  = blockIdx.x >> 4;
  const int k0 = (blockIdx.x & 15) * 64;
  const float* W = (w == 0) ? Wq : ((w == 1) ? Wk : Wv);

#pragma unroll
  for (int i = 0; i < 4; ++i) {
    int kl  = (t >> 4) + 16 * i;
    int col = (t & 15) * 4;
    float4 u = *(const float4*)(W + (size_t)(k0 + kl) * H_ + col);
    tile[kl][col + 0] = u.x; tile[kl][col + 1] = u.y;
    tile[kl][col + 2] = u.z; tile[kl][col + 3] = u.w;
  }
  __syncthreads();
#pragma unroll
  for (int i = 0; i < 4; ++i) {
    int h  = (t >> 4) + 16 * i;
    int kl = (t & 15) * 4;
    bf16x4 v;
    v[0] = (bf16_t)tile[kl + 0][h]; v[1] = (bf16_t)tile[kl + 1][h];
    v[2] = (bf16_t)tile[kl + 2][h]; v[3] = (bf16_t)tile[kl + 3][h];
    *(bf16x4*)(Wt + (size_t)w * 65536 + (size_t)h * C_ + k0 + kl) = v;
  }
}

// ---------------------------------------------------------------------------
// Kernel 2: QKV projection v4. BM=16, grid 1024 (4 blocks/CU, 16 waves/CU).
// No LDS, no barriers: per-wave depth-2 register pipeline (hand-unrolled x2
// so all stage indices are compile-time). Wave = 16 rows x 48 cols (1x3 frags).
// q written scaled by 0.125; v written transposed vt[b][h][t].
// ---------------------------------------------------------------------------
__global__ __launch_bounds__(256) void qkv_kernel(
    const float* __restrict__ x, const bf16_t* __restrict__ Wt,
    bf16_t* __restrict__ qb, bf16_t* __restrict__ kb, bf16_t* __restrict__ vt) {
  const int wave = threadIdx.x >> 6;
  const int lane = threadIdx.x & 63;
  const int l15  = lane & 15;
  const int lq   = lane >> 4;
  const int row0 = blockIdx.x * 16;

  int wsel_[3], h_[3];
  const bf16_t* bp[3];
#pragma unroll
  for (int j = 0; j < 3; ++j) {
    int col  = wave * 48 + j * 16 + l15;
    wsel_[j] = col >> 6;
    h_[j]    = col & 63;
    bp[j] = Wt + (size_t)(wsel_[j] * 64 + h_[j]) * C_ + lq * 8;
  }
  const float* ap = x + (size_t)(row0 + l15) * C_ + lq * 8;

  f32x4 acc[3];
#pragma unroll
  for (int j = 0; j < 3; ++j) acc[j] = (f32x4){0.f, 0.f, 0.f, 0.f};

  // depth-2 stage registers (slot = compile-time)
  float4 a0_0, a1_0, a0_1, a1_1;
  bf16x8 b_0[3], b_1[3];
  a0_0 = *(const float4*)(ap);       a1_0 = *(const float4*)(ap + 4);
  a0_1 = *(const float4*)(ap + 32);  a1_1 = *(const float4*)(ap + 36);
#pragma unroll
  for (int j = 0; j < 3; ++j) {
    b_0[j] = *(const bf16x8*)(bp[j]);
    b_1[j] = *(const bf16x8*)(bp[j] + 32);
  }

#define QKV_STEP(A0, A1, BREG, KK)                                           \
  {                                                                          \
    bf16x8 af;                                                               \
    af[0] = (bf16_t)A0.x; af[1] = (bf16_t)A0.y;                              \
    af[2] = (bf16_t)A0.z; af[3] = (bf16_t)A0.w;                              \
    af[4] = (bf16_t)A1.x; af[5] = (bf16_t)A1.y;                              \
    af[6] = (bf16_t)A1.z; af[7] = (bf16_t)A1.w;                              \
    bf16x8 bc0 = BREG[0], bc1 = BREG[1], bc2 = BREG[2];                      \
    if ((KK) + 2 < 32) {                                                     \
      A0 = *(const float4*)(ap + ((KK) + 2) * 32);                           \
      A1 = *(const float4*)(ap + ((KK) + 2) * 32 + 4);                       \
      BREG[0] = *(const bf16x8*)(bp[0] + ((KK) + 2) * 32);                   \
      BREG[1] = *(const bf16x8*)(bp[1] + ((KK) + 2) * 32);                   \
      BREG[2] = *(const bf16x8*)(bp[2] + ((KK) + 2) * 32);                   \
    }                                                                        \
    acc[0] = __builtin_amdgcn_mfma_f32_16x16x32_bf16(af, bc0, acc[0], 0, 0, 0); \
    acc[1] = __builtin_amdgcn_mfma_f32_16x16x32_bf16(af, bc1, acc[1], 0, 0, 0); \
    acc[2] = __builtin_amdgcn_mfma_f32_16x16x32_bf16(af, bc2, acc[2], 0, 0, 0); \
  }

  for (int k = 0; k < 32; k += 2) {
    QKV_STEP(a0_0, a1_0, b_0, k);
    QKV_STEP(a0_1, a1_1, b_1, k + 1);
  }
#undef QKV_STEP

#pragma unroll
  for (int j = 0; j < 3; ++j)
#pragma unroll
    for (int r = 0; r < 4; ++r) {
      int mm  = row0 + lq * 4 + r;
      float v = acc[j][r];
      if (wsel_[j] == 0) {
        qb[(size_t)mm * H_ + h_[j]] = (bf16_t)(v * 0.125f);
      } else if (wsel_[j] == 1) {
        kb[(size_t)mm * H_ + h_[j]] = (bf16_t)v;
      } else {
        int bb = mm >> 11, tt = mm & 2047;
        vt[((size_t)bb * H_ + h_[j]) * T_ + tt] = (bf16_t)v;
      }
    }
}

// ---------------------------------------------------------------------------
// Kernel 3: causal flash attention, split-KV, SWAPPED QK^T (in-register
// softmax). Grid 256 = (b, 64-row q-tile). Block = 1024 threads = 16 waves:
//   wave w: rg = w&3 (16 q-rows), ch = w>>2 (kv chunk, kt = ch, ch+4, ...).
// S^T = mfma(K, Q): lane (l15=q-col, lq) holds 16 k-values in-register ->
// softmax needs only 2 shfl_xor per tile, all q-rows in parallel.
// LAYOUT NOTE: softmax state (m_run,l_run,corr) is per-lane q = l15;
// oacc[nh][r] is q = lq*4+r. The in-loop rescale must TRANSPOSE corr:
// corr4[r] = shfl(corr, lq*4+r). (R4 bug: applied corr untransposed.)
// ---------------------------------------------------------------------------
__global__ __launch_bounds__(1024) void attn_kernel(
    const bf16_t* __restrict__ qb, const bf16_t* __restrict__ kb,
    const bf16_t* __restrict__ vt, float* __restrict__ out) {
  __shared__ __align__(16) char smem[51200];
  bf16_t (*plds)[16][72] = (bf16_t (*)[16][72])smem;      // [wave][q][k] P strip
  float (*co)[4][16][64] = (float (*)[4][16][64])smem;    // [ch-1][rg][row][h]
  float (*cml)[4][16][2] = (float (*)[4][16][2])(smem + 49152);  // [ch][rg][q][{m,l}]

  const int wave = threadIdx.x >> 6;
  const int lane = threadIdx.x & 63;
  const int l15  = lane & 15;
  const int lq   = lane >> 4;
  const int rg   = wave & 3;
  const int ch   = wave >> 2;
  const int b    = blockIdx.x >> 5;
  const int qi   = blockIdx.x & 31;
  const bf16_t* qB = qb + (size_t)b * T_ * H_;
  const bf16_t* kB = kb + (size_t)b * T_ * H_;
  const bf16_t* vB = vt + (size_t)b * H_ * T_;
  const int rowbase = qi * 64 + rg * 16;

  bf16x8 qf[2];
#pragma unroll
  for (int k0 = 0; k0 < 2; ++k0)
    qf[k0] = *(const bf16x8*)(qB + (size_t)(rowbase + l15) * H_ + k0 * 32 + lq * 8);

  float m_run = -1e30f, l_run = 0.f;  // per-lane: q-row = rowbase + l15
  f32x4 oacc[4];
#pragma unroll
  for (int nh = 0; nh < 4; ++nh) oacc[nh] = (f32x4){0.f, 0.f, 0.f, 0.f};

  for (int kt = ch; kt <= qi; kt += 4) {
    bf16x8 kf[4][2];
#pragma unroll
    for (int n = 0; n < 4; ++n)
#pragma unroll
      for (int k0 = 0; k0 < 2; ++k0)
        kf[n][k0] = *(const bf16x8*)(kB + (size_t)(kt * 64 + n * 16 + l15) * H_ + k0 * 32 + lq * 8);

    // S^T tile: sacc[n] rows = k (n*16 + lq*4 + r), col = q (l15)
    f32x4 sacc[4];
#pragma unroll
    for (int n = 0; n < 4; ++n) sacc[n] = (f32x4){0.f, 0.f, 0.f, 0.f};
    __builtin_amdgcn_s_setprio(1);
#pragma unroll
    for (int n = 0; n < 4; ++n)
#pragma unroll
      for (int k0 = 0; k0 < 2; ++k0)
        sacc[n] = __builtin_amdgcn_mfma_f32_16x16x32_bf16(kf[n][k0], qf[k0], sacc[n], 0, 0, 0);
    __builtin_amdgcn_s_setprio(0);

    // V loads fly during the softmax VALU phase
    bf16x8 vf[4][2];
#pragma unroll
    for (int nh = 0; nh < 4; ++nh)
#pragma unroll
      for (int k0 = 0; k0 < 2; ++k0)
        vf[nh][k0] = *(const bf16x8*)(vB + (size_t)(nh * 16 + l15) * T_ + kt * 64 + k0 * 32 + lq * 8);

    if (kt == qi) {  // diagonal tile: mask k_local > q_local
#pragma unroll
      for (int n = 0; n < 4; ++n)
#pragma unroll
        for (int r = 0; r < 4; ++r)
          if (n * 16 + lq * 4 + r > rg * 16 + l15) sacc[n][r] = -1e30f;
    }

    // in-register softmax: lane owns q-col l15 with 16 k-values
    float mx = -1e30f;
#pragma unroll
    for (int n = 0; n < 4; ++n)
#pragma unroll
      for (int r = 0; r < 4; ++r) mx = fmaxf(mx, sacc[n][r]);
    mx = fmaxf(mx, __shfl_xor(mx, 16));
    mx = fmaxf(mx, __shfl_xor(mx, 32));
    float mnew = fmaxf(m_run, mx);
    float corr = __expf(m_run - mnew);
    float psum = 0.f;
#pragma unroll
    for (int n = 0; n < 4; ++n)
#pragma unroll
      for (int r = 0; r < 4; ++r) {
        float p = __expf(sacc[n][r] - mnew);
        sacc[n][r] = p;
        psum += p;
      }
    psum += __shfl_xor(psum, 16);
    psum += __shfl_xor(psum, 32);
    l_run = l_run * corr + psum;
    m_run = mnew;

    // transpose corr into the oacc layout (q = lq*4+r): lane lq*4+r holds
    // l15 == lq*4+r (its lq==0), and corr is uniform across lq-replicas.
    float corr4[4];
#pragma unroll
    for (int r = 0; r < 4; ++r) corr4[r] = __shfl(corr, lq * 4 + r);
#pragma unroll
    for (int nh = 0; nh < 4; ++nh)
#pragma unroll
      for (int r = 0; r < 4; ++r) oacc[nh][r] *= corr4[r];

    // P^T -> LDS strip (transposed write): plds[wave][q=l15][k]
#pragma unroll
    for (int n = 0; n < 4; ++n) {
      bf16x4 pk;
#pragma unroll
      for (int r = 0; r < 4; ++r) pk[r] = (bf16_t)sacc[n][r];
      *(bf16x4*)&plds[wave][l15][n * 16 + lq * 4] = pk;
    }

    // A-frag read: P[q=l15][k=lq*8+j] (same-wave; compiler inserts lgkmcnt)
    bf16x8 pa[2];
    pa[0] = *(const bf16x8*)&plds[wave][l15][lq * 8];
    pa[1] = *(const bf16x8*)&plds[wave][l15][32 + lq * 8];

    __builtin_amdgcn_s_setprio(1);
#pragma unroll
    for (int nh = 0; nh < 4; ++nh)
#pragma unroll
      for (int k0 = 0; k0 < 2; ++k0)
        oacc[nh] = __builtin_amdgcn_mfma_f32_16x16x32_bf16(pa[k0], vf[nh][k0], oacc[nh], 0, 0, 0);
    __builtin_amdgcn_s_setprio(0);
  }

  __syncthreads();  // plds reads done everywhere; smem becomes combine buffers

  if (lq == 0) {  // lane l15 holds (m,l) for q-row l15
    cml[ch][rg][l15][0] = m_run;
    cml[ch][rg][l15][1] = l_run;
  }
  if (ch > 0) {
#pragma unroll
    for (int r = 0; r < 4; ++r) {
      int row = lq * 4 + r;
#pragma unroll
      for (int nh = 0; nh < 4; ++nh)
        co[ch - 1][rg][row][nh * 16 + l15] = oacc[nh][r];
    }
  }
  __syncthreads();

  if (ch == 0) {
#pragma unroll
    for (int r = 0; r < 4; ++r) {
      int row = lq * 4 + r;                     // oacc row = q (rg*16 + row)
      float M = cml[0][rg][row][0];
      float L = cml[0][rg][row][1];
      float o[4];
#pragma unroll
      for (int nh = 0; nh < 4; ++nh) o[nh] = oacc[nh][r];
#pragma unroll
      for (int s = 1; s < 4; ++s) {
        float ms = cml[s][rg][row][0];
        float ls = cml[s][rg][row][1];
        float Mn = fmaxf(M, ms);
        float a  = __expf(M - Mn);
        float bs = __expf(ms - Mn);
        L = L * a + ls * bs;
#pragma unroll
        for (int nh = 0; nh < 4; ++nh)
          o[nh] = o[nh] * a + co[s - 1][rg][row][nh * 16 + l15] * bs;
        M = Mn;
      }
      float inv = 1.0f / L;
      int tt = rowbase + row;
#pragma unroll
      for (int nh = 0; nh < 4; ++nh)
        out[((size_t)b * T_ + tt) * H_ + nh * 16 + l15] = o[nh] * inv;
    }
  }
}

// ---------------------------------------------------------------------------
extern "C" void kernel_launch(void* const* d_in, const int* in_sizes, int n_in,
                              void* d_out, int out_size, void* d_ws, size_t ws_size,
                              hipStream_t stream) {
  const float* x  = (const float*)d_in[0];
  const float* Wq = (const float*)d_in[1];
  const float* Wk = (const float*)d_in[2];
  const float* Wv = (const float*)d_in[3];

  char* ws = (char*)d_ws;
  bf16_t* Wt = (bf16_t*)(ws);                    // 384 KB
  bf16_t* qb = (bf16_t*)(ws + (1u << 20));       // 2 MB (scaled q)
  bf16_t* kb = (bf16_t*)(ws + 3u * (1u << 20));  // 2 MB
  bf16_t* vt = (bf16_t*)(ws + 5u * (1u << 20));  // 2 MB (v transposed [b][h][t])
  float* outp = (float*)d_out;

  hipLaunchKernelGGL(wprep_kernel, dim3(48), dim3(256), 0, stream, Wq, Wk, Wv, Wt);
  hipLaunchKernelGGL(qkv_kernel, dim3(1024), dim3(256), 0, stream, x, Wt, qb, kb, vt);
  hipLaunchKernelGGL(attn_kernel, dim3(256), dim3(1024), 0, stream, qb, kb, vt, outp);
}

// Round 6
// 116.793 us; speedup vs baseline: 1.2231x; 1.2231x over previous
//
#include <hip/hip_runtime.h>
#include <hip/hip_bf16.h>

typedef __bf16 bf16_t;
typedef __attribute__((ext_vector_type(4))) __bf16 bf16x4;
typedef __attribute__((ext_vector_type(8))) __bf16 bf16x8;
typedef __attribute__((ext_vector_type(4))) float f32x4;

#define B_ 8
#define T_ 2048
#define C_ 1024
#define H_ 64

// ---------------------------------------------------------------------------
// Kernel 1: convert + transpose weights -> Wt[w][h][k] bf16 (w: 0=q,1=k,2=v)
// ---------------------------------------------------------------------------
__global__ __launch_bounds__(256) void wprep_kernel(
    const float* __restrict__ Wq, const float* __restrict__ Wk,
    const float* __restrict__ Wv, bf16_t* __restrict__ Wt) {
  __shared__ float tile[64][68];
  const int t  = threadIdx.x;
  const int w  = blockIdx.x >> 4;
  const int k0 = (blockIdx.x & 15) * 64;
  const float* W = (w == 0) ? Wq : ((w == 1) ? Wk : Wv);

#pragma unroll
  for (int i = 0; i < 4; ++i) {
    int kl  = (t >> 4) + 16 * i;
    int col = (t & 15) * 4;
    float4 u = *(const float4*)(W + (size_t)(k0 + kl) * H_ + col);
    tile[kl][col + 0] = u.x; tile[kl][col + 1] = u.y;
    tile[kl][col + 2] = u.z; tile[kl][col + 3] = u.w;
  }
  __syncthreads();
#pragma unroll
  for (int i = 0; i < 4; ++i) {
    int h  = (t >> 4) + 16 * i;
    int kl = (t & 15) * 4;
    bf16x4 v;
    v[0] = (bf16_t)tile[kl + 0][h]; v[1] = (bf16_t)tile[kl + 1][h];
    v[2] = (bf16_t)tile[kl + 2][h]; v[3] = (bf16_t)tile[kl + 3][h];
    *(bf16x4*)(Wt + (size_t)w * 65536 + (size_t)h * C_ + k0 + kl) = v;
  }
}

// ---------------------------------------------------------------------------
// Kernel 2: QKV projection v5. Grid 512 (2 blocks/CU). Block = 32 rows x 192
// cols, 4 waves; wave = 32 rows x 48 cols (2x3 frags). BK=64 -> 16 phases.
// 4-buffer XOR-swizzled LDS for x; x loads issued at phase p are ds_written
// at p+2, consumed at p+3 (wait-distance ~2 phases ~ HBM latency).
// B-frags register-prefetched 1 phase ahead (L2-resident Wt).
// Fully unrolled so all stage-register indices are compile-time.
// ---------------------------------------------------------------------------
__global__ __launch_bounds__(256) void qkv_kernel(
    const float* __restrict__ x, const bf16_t* __restrict__ Wt,
    bf16_t* __restrict__ qb, bf16_t* __restrict__ kb, bf16_t* __restrict__ vt) {
  __shared__ __align__(16) char xs[4][8192];  // 4 bufs x 32 rows x 256B
  const int tid  = threadIdx.x;
  const int wave = tid >> 6;
  const int lane = tid & 63;
  const int l15  = lane & 15;
  const int lq   = lane >> 4;
  const int row0 = blockIdx.x * 32;

  int wsel_[3], h_[3];
  const bf16_t* bp[3];
#pragma unroll
  for (int j = 0; j < 3; ++j) {
    int col  = wave * 48 + j * 16 + l15;
    wsel_[j] = col >> 6;
    h_[j]    = col & 63;
    bp[j] = Wt + (size_t)(wsel_[j] * 64 + h_[j]) * C_ + lq * 8;
  }

  // staging map: thread -> row (srow), float4-group (fg); swizzled writes
  const int srow = tid >> 3;
  const int fg   = tid & 7;
  const float* src = x + (size_t)(row0 + srow) * C_ + fg * 8;
  const int ssw = (srow & 7) << 4;
  const int wb0 = srow * 256 + ((fg * 32) ^ ssw);
  const int wb1 = srow * 256 + ((fg * 32 + 16) ^ ssw);

  // read map: row r = m*16+l15 (swizzle dep only on l15&7)
  const int rsw = (l15 & 7) << 4;

  f32x4 acc[2][3];
#pragma unroll
  for (int m = 0; m < 2; ++m)
#pragma unroll
    for (int j = 0; j < 3; ++j) acc[m][j] = (f32x4){0.f, 0.f, 0.f, 0.f};

  float4 sA[2][2];      // [set][2x float4]; set = target-phase & 1
  bf16x8 bf[2][2][3];   // [set][ks][j];    set = phase & 1

  // prologue: stage phase 0 directly, preload sA(ph1, ph2), B(ph0)
  {
    float4 t0 = *(const float4*)(src);
    float4 t1 = *(const float4*)(src + 4);
    *(float4*)(&xs[0][0] + 0 + wb0) = t0;
    *(float4*)(&xs[0][0] + 0 + wb1) = t1;
  }
  sA[1][0] = *(const float4*)(src + 64);  sA[1][1] = *(const float4*)(src + 68);
  sA[0][0] = *(const float4*)(src + 128); sA[0][1] = *(const float4*)(src + 132);
#pragma unroll
  for (int ks = 0; ks < 2; ++ks)
#pragma unroll
    for (int j = 0; j < 3; ++j) bf[0][ks][j] = *(const bf16x8*)(bp[j] + ks * 32);
  __syncthreads();

#pragma unroll
  for (int p = 0; p < 16; ++p) {
    // a) prefetch next phase's B fragments (L2)
    if (p + 1 < 16) {
#pragma unroll
      for (int ks = 0; ks < 2; ++ks)
#pragma unroll
        for (int j = 0; j < 3; ++j)
          bf[(p + 1) & 1][ks][j] = *(const bf16x8*)(bp[j] + (p + 1) * 64 + ks * 32);
    }

    // b) compute from xs[p&3]
    const char* bufc = &xs[p & 3][0];
    bf16x8 af[2][2];
#pragma unroll
    for (int m = 0; m < 2; ++m) {
      const int rbase = (m * 16 + l15) * 256;
#pragma unroll
      for (int ks = 0; ks < 2; ++ks) {
        f32x4 a0 = *(const f32x4*)(bufc + rbase + ((ks * 128 + lq * 32) ^ rsw));
        f32x4 a1 = *(const f32x4*)(bufc + rbase + ((ks * 128 + lq * 32 + 16) ^ rsw));
        bf16x8 a;
        a[0] = (bf16_t)a0[0]; a[1] = (bf16_t)a0[1]; a[2] = (bf16_t)a0[2]; a[3] = (bf16_t)a0[3];
        a[4] = (bf16_t)a1[0]; a[5] = (bf16_t)a1[1]; a[6] = (bf16_t)a1[2]; a[7] = (bf16_t)a1[3];
        af[m][ks] = a;
      }
    }
    __builtin_amdgcn_s_setprio(1);
#pragma unroll
    for (int ks = 0; ks < 2; ++ks)
#pragma unroll
      for (int m = 0; m < 2; ++m)
#pragma unroll
        for (int j = 0; j < 3; ++j)
          acc[m][j] = __builtin_amdgcn_mfma_f32_16x16x32_bf16(af[m][ks], bf[p & 1][ks][j], acc[m][j], 0, 0, 0);
    __builtin_amdgcn_s_setprio(0);

    // c) write-late: stage phase p+1 (regs issued at p-2), then reissue set
    if (p + 1 < 16) {
      char* bufw = &xs[(p + 1) & 3][0];
      *(float4*)(bufw + wb0) = sA[(p + 1) & 1][0];
      *(float4*)(bufw + wb1) = sA[(p + 1) & 1][1];
    }
    if (p + 3 < 16) {
      sA[(p + 1) & 1][0] = *(const float4*)(src + (p + 3) * 64);
      sA[(p + 1) & 1][1] = *(const float4*)(src + (p + 3) * 64 + 4);
    }
    __syncthreads();
  }

  // epilogue
#pragma unroll
  for (int m = 0; m < 2; ++m)
#pragma unroll
    for (int j = 0; j < 3; ++j)
#pragma unroll
      for (int r = 0; r < 4; ++r) {
        int mm  = row0 + m * 16 + lq * 4 + r;
        float v = acc[m][j][r];
        if (wsel_[j] == 0) {
          qb[(size_t)mm * H_ + h_[j]] = (bf16_t)(v * 0.125f);
        } else if (wsel_[j] == 1) {
          kb[(size_t)mm * H_ + h_[j]] = (bf16_t)v;
        } else {
          int bb = mm >> 11, tt = mm & 2047;
          vt[((size_t)bb * H_ + h_[j]) * T_ + tt] = (bf16_t)v;
        }
      }
}

// ---------------------------------------------------------------------------
// Kernel 3a: causal flash attention PARTIALS. Grid 1024 = (b, qi, ch):
//   bid = (b<<7)|(qi<<2)|ch. Block = 256 threads = 4 waves (rg = wave).
// Wave: 16 q-rows, kv-tiles kt = ch, ch+4, ..., <= qi. Small blocks (9KB LDS)
// -> ~8 blocks/CU resident, HW backfill erases causal imbalance.
// Swapped QK^T in-register softmax (see R4/R5 layout note: corr transposed
// via shfl into the oacc layout). Partial (m,l,O) written to workspace.
// ---------------------------------------------------------------------------
__global__ __launch_bounds__(256) void attn_partial(
    const bf16_t* __restrict__ qb, const bf16_t* __restrict__ kb,
    const bf16_t* __restrict__ vt, float* __restrict__ opart,
    float* __restrict__ ml) {
  __shared__ bf16_t plds[4][16][72];
  const int wave = threadIdx.x >> 6;  // = rg
  const int lane = threadIdx.x & 63;
  const int l15  = lane & 15;
  const int lq   = lane >> 4;
  const int bid  = blockIdx.x;
  const int b    = bid >> 7;
  const int qi   = (bid >> 2) & 31;
  const int ch   = bid & 3;
  const bf16_t* qB = qb + (size_t)b * T_ * H_;
  const bf16_t* kB = kb + (size_t)b * T_ * H_;
  const bf16_t* vB = vt + (size_t)b * H_ * T_;
  const int rowbase = qi * 64 + wave * 16;

  bf16x8 qf[2];
#pragma unroll
  for (int k0 = 0; k0 < 2; ++k0)
    qf[k0] = *(const bf16x8*)(qB + (size_t)(rowbase + l15) * H_ + k0 * 32 + lq * 8);

  float m_run = -1e30f, l_run = 0.f;  // per-lane q-row = rowbase + l15
  f32x4 oacc[4];
#pragma unroll
  for (int nh = 0; nh < 4; ++nh) oacc[nh] = (f32x4){0.f, 0.f, 0.f, 0.f};

  for (int kt = ch; kt <= qi; kt += 4) {
    bf16x8 kf[4][2];
#pragma unroll
    for (int n = 0; n < 4; ++n)
#pragma unroll
      for (int k0 = 0; k0 < 2; ++k0)
        kf[n][k0] = *(const bf16x8*)(kB + (size_t)(kt * 64 + n * 16 + l15) * H_ + k0 * 32 + lq * 8);

    // S^T tile: sacc[n] row = k (n*16+lq*4+r), col = q (l15)
    f32x4 sacc[4];
#pragma unroll
    for (int n = 0; n < 4; ++n) sacc[n] = (f32x4){0.f, 0.f, 0.f, 0.f};
    __builtin_amdgcn_s_setprio(1);
#pragma unroll
    for (int n = 0; n < 4; ++n)
#pragma unroll
      for (int k0 = 0; k0 < 2; ++k0)
        sacc[n] = __builtin_amdgcn_mfma_f32_16x16x32_bf16(kf[n][k0], qf[k0], sacc[n], 0, 0, 0);
    __builtin_amdgcn_s_setprio(0);

    // V loads fly during the softmax VALU phase
    bf16x8 vf[4][2];
#pragma unroll
    for (int nh = 0; nh < 4; ++nh)
#pragma unroll
      for (int k0 = 0; k0 < 2; ++k0)
        vf[nh][k0] = *(const bf16x8*)(vB + (size_t)(nh * 16 + l15) * T_ + kt * 64 + k0 * 32 + lq * 8);

    if (kt == qi) {  // diagonal tile: mask k_local > q_local
#pragma unroll
      for (int n = 0; n < 4; ++n)
#pragma unroll
        for (int r = 0; r < 4; ++r)
          if (n * 16 + lq * 4 + r > wave * 16 + l15) sacc[n][r] = -1e30f;
    }

    // in-register softmax: lane owns q-col l15 (16 k-values in-register)
    float mx = -1e30f;
#pragma unroll
    for (int n = 0; n < 4; ++n)
#pragma unroll
      for (int r = 0; r < 4; ++r) mx = fmaxf(mx, sacc[n][r]);
    mx = fmaxf(mx, __shfl_xor(mx, 16));
    mx = fmaxf(mx, __shfl_xor(mx, 32));
    float mnew = fmaxf(m_run, mx);
    float corr = __expf(m_run - mnew);
    float psum = 0.f;
#pragma unroll
    for (int n = 0; n < 4; ++n)
#pragma unroll
      for (int r = 0; r < 4; ++r) {
        float p = __expf(sacc[n][r] - mnew);
        sacc[n][r] = p;
        psum += p;
      }
    psum += __shfl_xor(psum, 16);
    psum += __shfl_xor(psum, 32);
    l_run = l_run * corr + psum;
    m_run = mnew;

    // transpose corr into oacc layout (q = lq*4+r)
    float corr4[4];
#pragma unroll
    for (int r = 0; r < 4; ++r) corr4[r] = __shfl(corr, lq * 4 + r);
#pragma unroll
    for (int nh = 0; nh < 4; ++nh)
#pragma unroll
      for (int r = 0; r < 4; ++r) oacc[nh][r] *= corr4[r];

    // P^T -> per-wave LDS strip: plds[wave][q=l15][k]
#pragma unroll
    for (int n = 0; n < 4; ++n) {
      bf16x4 pk;
#pragma unroll
      for (int r = 0; r < 4; ++r) pk[r] = (bf16_t)sacc[n][r];
      *(bf16x4*)&plds[wave][l15][n * 16 + lq * 4] = pk;
    }
    bf16x8 pa[2];
    pa[0] = *(const bf16x8*)&plds[wave][l15][lq * 8];
    pa[1] = *(const bf16x8*)&plds[wave][l15][32 + lq * 8];

    __builtin_amdgcn_s_setprio(1);
#pragma unroll
    for (int nh = 0; nh < 4; ++nh)
#pragma unroll
      for (int k0 = 0; k0 < 2; ++k0)
        oacc[nh] = __builtin_amdgcn_mfma_f32_16x16x32_bf16(pa[k0], vf[nh][k0], oacc[nh], 0, 0, 0);
    __builtin_amdgcn_s_setprio(0);
  }

  // write partials: opart[bid*64 + qrow_local][64 cols], ml[bid*64 + q][2]
  const int prow = bid * 64 + wave * 16;
#pragma unroll
  for (int r = 0; r < 4; ++r)
#pragma unroll
    for (int nh = 0; nh < 4; ++nh)
      opart[(size_t)(prow + lq * 4 + r) * 64 + nh * 16 + l15] = oacc[nh][r];
  if (lq == 0) {
    ml[(size_t)(prow + l15) * 2 + 0] = m_run;
    ml[(size_t)(prow + l15) * 2 + 1] = l_run;
  }
}

// ---------------------------------------------------------------------------
// Kernel 3b: combine 4 kv-chunk partials per (b, qi). Grid 256 = (b<<5)|qi,
// 256 threads: thread -> row = t>>2 (64 rows), 16-col group = t&2 ... (t&3).
// ---------------------------------------------------------------------------
__global__ __launch_bounds__(256) void attn_combine(
    const float* __restrict__ opart, const float* __restrict__ ml,
    float* __restrict__ out) {
  const int cid = blockIdx.x;       // (b<<5)|qi
  const int b   = cid >> 5;
  const int qi  = cid & 31;
  const int row = threadIdx.x >> 2;
  const int cg  = threadIdx.x & 3;  // 16-col group
  const int pbase = cid * 4;        // partial bid base

  const float* ml0 = ml + ((size_t)(pbase * 64) + row) * 2;
  float M = ml0[0];
  float L = ml0[1];
  float4 o[4];
  const float* p0 = opart + ((size_t)(pbase * 64) + row) * 64 + cg * 16;
#pragma unroll
  for (int g = 0; g < 4; ++g) o[g] = *(const float4*)(p0 + g * 4);

#pragma unroll
  for (int s = 1; s < 4; ++s) {
    const float* mls = ml + ((size_t)((pbase + s) * 64) + row) * 2;
    float ms = mls[0];
    float ls = mls[1];
    float Mn = fmaxf(M, ms);
    float a  = __expf(M - Mn);
    float bs = __expf(ms - Mn);
    const float* ps = opart + ((size_t)((pbase + s) * 64) + row) * 64 + cg * 16;
#pragma unroll
    for (int g = 0; g < 4; ++g) {
      float4 os = *(const float4*)(ps + g * 4);
      o[g].x = o[g].x * a + os.x * bs;
      o[g].y = o[g].y * a + os.y * bs;
      o[g].z = o[g].z * a + os.z * bs;
      o[g].w = o[g].w * a + os.w * bs;
    }
    L = L * a + ls * bs;
    M = Mn;
  }
  float inv = 1.0f / L;
  float* op = out + ((size_t)b * T_ + qi * 64 + row) * H_ + cg * 16;
#pragma unroll
  for (int g = 0; g < 4; ++g) {
    float4 v = o[g];
    v.x *= inv; v.y *= inv; v.z *= inv; v.w *= inv;
    *(float4*)(op + g * 4) = v;
  }
}

// ---------------------------------------------------------------------------
extern "C" void kernel_launch(void* const* d_in, const int* in_sizes, int n_in,
                              void* d_out, int out_size, void* d_ws, size_t ws_size,
                              hipStream_t stream) {
  const float* x  = (const float*)d_in[0];
  const float* Wq = (const float*)d_in[1];
  const float* Wk = (const float*)d_in[2];
  const float* Wv = (const float*)d_in[3];

  char* ws = (char*)d_ws;
  bf16_t* Wt  = (bf16_t*)(ws);                     // 384 KB
  bf16_t* qb  = (bf16_t*)(ws + (1u << 20));        // 2 MB (scaled q)
  bf16_t* kb  = (bf16_t*)(ws + 3u * (1u << 20));   // 2 MB
  bf16_t* vt  = (bf16_t*)(ws + 5u * (1u << 20));   // 2 MB (v transposed [b][h][t])
  float* opart = (float*)(ws + 8u * (1u << 20));   // 16 MB (1024*64*64 f32)
  float* mlbuf = (float*)(ws + 24u * (1u << 20));  // 512 KB
  float* outp  = (float*)d_out;

  hipLaunchKernelGGL(wprep_kernel, dim3(48), dim3(256), 0, stream, Wq, Wk, Wv, Wt);
  hipLaunchKernelGGL(qkv_kernel, dim3(512), dim3(256), 0, stream, x, Wt, qb, kb, vt);
  hipLaunchKernelGGL(attn_partial, dim3(1024), dim3(256), 0, stream, qb, kb, vt, opart, mlbuf);
  hipLaunchKernelGGL(attn_combine, dim3(256), dim3(256), 0, stream, opart, mlbuf, outp);
}

// Round 7
// 103.740 us; speedup vs baseline: 1.3770x; 1.1258x over previous
//
#include <hip/hip_runtime.h>
#include <hip/hip_bf16.h>

typedef __bf16 bf16_t;
typedef __attribute__((ext_vector_type(4))) __bf16 bf16x4;
typedef __attribute__((ext_vector_type(8))) __bf16 bf16x8;
typedef __attribute__((ext_vector_type(4))) float f32x4;

#define B_ 8
#define T_ 2048
#define C_ 1024
#define H_ 64

// q-scale: H^-0.5 * log2(e)  (softmax computed in exp2 domain)
#define QSCALE 0.18033688f

// ---------------------------------------------------------------------------
// Kernel 1: convert + transpose weights -> Wt[w][h][k] bf16 (w: 0=q,1=k,2=v)
// ---------------------------------------------------------------------------
__global__ __launch_bounds__(256) void wprep_kernel(
    const float* __restrict__ Wq, const float* __restrict__ Wk,
    const float* __restrict__ Wv, bf16_t* __restrict__ Wt) {
  __shared__ float tile[64][68];
  const int t  = threadIdx.x;
  const int w  = blockIdx.x >> 4;
  const int k0 = (blockIdx.x & 15) * 64;
  const float* W = (w == 0) ? Wq : ((w == 1) ? Wk : Wv);

#pragma unroll
  for (int i = 0; i < 4; ++i) {
    int kl  = (t >> 4) + 16 * i;
    int col = (t & 15) * 4;
    float4 u = *(const float4*)(W + (size_t)(k0 + kl) * H_ + col);
    tile[kl][col + 0] = u.x; tile[kl][col + 1] = u.y;
    tile[kl][col + 2] = u.z; tile[kl][col + 3] = u.w;
  }
  __syncthreads();
#pragma unroll
  for (int i = 0; i < 4; ++i) {
    int h  = (t >> 4) + 16 * i;
    int kl = (t & 15) * 4;
    bf16x4 v;
    v[0] = (bf16_t)tile[kl + 0][h]; v[1] = (bf16_t)tile[kl + 1][h];
    v[2] = (bf16_t)tile[kl + 2][h]; v[3] = (bf16_t)tile[kl + 3][h];
    *(bf16x4*)(Wt + (size_t)w * 65536 + (size_t)h * C_ + k0 + kl) = v;
  }
}

// ---------------------------------------------------------------------------
// Kernel 2: QKV projection v5 (unchanged from R6 except q-scale constant).
// ---------------------------------------------------------------------------
__global__ __launch_bounds__(256) void qkv_kernel(
    const float* __restrict__ x, const bf16_t* __restrict__ Wt,
    bf16_t* __restrict__ qb, bf16_t* __restrict__ kb, bf16_t* __restrict__ vt) {
  __shared__ __align__(16) char xs[4][8192];  // 4 bufs x 32 rows x 256B
  const int tid  = threadIdx.x;
  const int wave = tid >> 6;
  const int lane = tid & 63;
  const int l15  = lane & 15;
  const int lq   = lane >> 4;
  const int row0 = blockIdx.x * 32;

  int wsel_[3], h_[3];
  const bf16_t* bp[3];
#pragma unroll
  for (int j = 0; j < 3; ++j) {
    int col  = wave * 48 + j * 16 + l15;
    wsel_[j] = col >> 6;
    h_[j]    = col & 63;
    bp[j] = Wt + (size_t)(wsel_[j] * 64 + h_[j]) * C_ + lq * 8;
  }

  const int srow = tid >> 3;
  const int fg   = tid & 7;
  const float* src = x + (size_t)(row0 + srow) * C_ + fg * 8;
  const int ssw = (srow & 7) << 4;
  const int wb0 = srow * 256 + ((fg * 32) ^ ssw);
  const int wb1 = srow * 256 + ((fg * 32 + 16) ^ ssw);
  const int rsw = (l15 & 7) << 4;

  f32x4 acc[2][3];
#pragma unroll
  for (int m = 0; m < 2; ++m)
#pragma unroll
    for (int j = 0; j < 3; ++j) acc[m][j] = (f32x4){0.f, 0.f, 0.f, 0.f};

  float4 sA[2][2];
  bf16x8 bf[2][2][3];

  {
    float4 t0 = *(const float4*)(src);
    float4 t1 = *(const float4*)(src + 4);
    *(float4*)(&xs[0][0] + 0 + wb0) = t0;
    *(float4*)(&xs[0][0] + 0 + wb1) = t1;
  }
  sA[1][0] = *(const float4*)(src + 64);  sA[1][1] = *(const float4*)(src + 68);
  sA[0][0] = *(const float4*)(src + 128); sA[0][1] = *(const float4*)(src + 132);
#pragma unroll
  for (int ks = 0; ks < 2; ++ks)
#pragma unroll
    for (int j = 0; j < 3; ++j) bf[0][ks][j] = *(const bf16x8*)(bp[j] + ks * 32);
  __syncthreads();

#pragma unroll
  for (int p = 0; p < 16; ++p) {
    if (p + 1 < 16) {
#pragma unroll
      for (int ks = 0; ks < 2; ++ks)
#pragma unroll
        for (int j = 0; j < 3; ++j)
          bf[(p + 1) & 1][ks][j] = *(const bf16x8*)(bp[j] + (p + 1) * 64 + ks * 32);
    }

    const char* bufc = &xs[p & 3][0];
    bf16x8 af[2][2];
#pragma unroll
    for (int m = 0; m < 2; ++m) {
      const int rbase = (m * 16 + l15) * 256;
#pragma unroll
      for (int ks = 0; ks < 2; ++ks) {
        f32x4 a0 = *(const f32x4*)(bufc + rbase + ((ks * 128 + lq * 32) ^ rsw));
        f32x4 a1 = *(const f32x4*)(bufc + rbase + ((ks * 128 + lq * 32 + 16) ^ rsw));
        bf16x8 a;
        a[0] = (bf16_t)a0[0]; a[1] = (bf16_t)a0[1]; a[2] = (bf16_t)a0[2]; a[3] = (bf16_t)a0[3];
        a[4] = (bf16_t)a1[0]; a[5] = (bf16_t)a1[1]; a[6] = (bf16_t)a1[2]; a[7] = (bf16_t)a1[3];
        af[m][ks] = a;
      }
    }
    __builtin_amdgcn_s_setprio(1);
#pragma unroll
    for (int ks = 0; ks < 2; ++ks)
#pragma unroll
      for (int m = 0; m < 2; ++m)
#pragma unroll
        for (int j = 0; j < 3; ++j)
          acc[m][j] = __builtin_amdgcn_mfma_f32_16x16x32_bf16(af[m][ks], bf[p & 1][ks][j], acc[m][j], 0, 0, 0);
    __builtin_amdgcn_s_setprio(0);

    if (p + 1 < 16) {
      char* bufw = &xs[(p + 1) & 3][0];
      *(float4*)(bufw + wb0) = sA[(p + 1) & 1][0];
      *(float4*)(bufw + wb1) = sA[(p + 1) & 1][1];
    }
    if (p + 3 < 16) {
      sA[(p + 1) & 1][0] = *(const float4*)(src + (p + 3) * 64);
      sA[(p + 1) & 1][1] = *(const float4*)(src + (p + 3) * 64 + 4);
    }
    __syncthreads();
  }

#pragma unroll
  for (int m = 0; m < 2; ++m)
#pragma unroll
    for (int j = 0; j < 3; ++j)
#pragma unroll
      for (int r = 0; r < 4; ++r) {
        int mm  = row0 + m * 16 + lq * 4 + r;
        float v = acc[m][j][r];
        if (wsel_[j] == 0) {
          qb[(size_t)mm * H_ + h_[j]] = (bf16_t)(v * QSCALE);
        } else if (wsel_[j] == 1) {
          kb[(size_t)mm * H_ + h_[j]] = (bf16_t)v;
        } else {
          int bb = mm >> 11, tt = mm & 2047;
          vt[((size_t)bb * H_ + h_[j]) * T_ + tt] = (bf16_t)v;
        }
      }
}

// ---------------------------------------------------------------------------
// Kernel 3a: causal flash attention PARTIALS, split-8.
// Grid 2048 = (b<<8)|(qi<<3)|ch. Block = 256 threads = 4 waves (rg = wave).
// Wave: 16 q-rows, kv-tiles kt = ch, ch+8, ... <= qi (max 4 tiles).
// Swapped QK^T in-register softmax in exp2 domain. Chain cuts:
//  - defer-rescale: corr path only when __any(mx > m_run)
//  - l kept as per-lane partial (each lq-replica owns distinct k's);
//    cross-lane reduced ONCE at the end, not per tile.
// Partial O -> bf16 workspace; (m, l) -> fp32.
// ---------------------------------------------------------------------------
__global__ __launch_bounds__(256) void attn_partial(
    const bf16_t* __restrict__ qb, const bf16_t* __restrict__ kb,
    const bf16_t* __restrict__ vt, bf16_t* __restrict__ opart,
    float* __restrict__ ml) {
  __shared__ bf16_t plds[4][16][72];
  const int wave = threadIdx.x >> 6;  // = rg
  const int lane = threadIdx.x & 63;
  const int l15  = lane & 15;
  const int lq   = lane >> 4;
  const int bid  = blockIdx.x;
  const int b    = bid >> 8;
  const int qi   = (bid >> 3) & 31;
  const int ch   = bid & 7;
  const bf16_t* qB = qb + (size_t)b * T_ * H_;
  const bf16_t* kB = kb + (size_t)b * T_ * H_;
  const bf16_t* vB = vt + (size_t)b * H_ * T_;
  const int rowbase = qi * 64 + wave * 16;

  bf16x8 qf[2];
#pragma unroll
  for (int k0 = 0; k0 < 2; ++k0)
    qf[k0] = *(const bf16x8*)(qB + (size_t)(rowbase + l15) * H_ + k0 * 32 + lq * 8);

  float m_run = -1e30f;   // per-lane q-row = rowbase + l15 (log2 domain)
  float l_part = 0.f;     // per-lane PARTIAL sum (this lane's k-slice only)
  f32x4 oacc[4];
#pragma unroll
  for (int nh = 0; nh < 4; ++nh) oacc[nh] = (f32x4){0.f, 0.f, 0.f, 0.f};

  for (int kt = ch; kt <= qi; kt += 8) {
    bf16x8 kf[4][2];
#pragma unroll
    for (int n = 0; n < 4; ++n)
#pragma unroll
      for (int k0 = 0; k0 < 2; ++k0)
        kf[n][k0] = *(const bf16x8*)(kB + (size_t)(kt * 64 + n * 16 + l15) * H_ + k0 * 32 + lq * 8);

    // S^T tile: sacc[n] row = k (n*16+lq*4+r), col = q (l15)
    f32x4 sacc[4];
#pragma unroll
    for (int n = 0; n < 4; ++n) sacc[n] = (f32x4){0.f, 0.f, 0.f, 0.f};
    __builtin_amdgcn_s_setprio(1);
#pragma unroll
    for (int n = 0; n < 4; ++n)
#pragma unroll
      for (int k0 = 0; k0 < 2; ++k0)
        sacc[n] = __builtin_amdgcn_mfma_f32_16x16x32_bf16(kf[n][k0], qf[k0], sacc[n], 0, 0, 0);
    __builtin_amdgcn_s_setprio(0);

    bf16x8 vf[4][2];
#pragma unroll
    for (int nh = 0; nh < 4; ++nh)
#pragma unroll
      for (int k0 = 0; k0 < 2; ++k0)
        vf[nh][k0] = *(const bf16x8*)(vB + (size_t)(nh * 16 + l15) * T_ + kt * 64 + k0 * 32 + lq * 8);

    if (kt == qi) {  // diagonal tile: mask k_local > q_local
#pragma unroll
      for (int n = 0; n < 4; ++n)
#pragma unroll
        for (int r = 0; r < 4; ++r)
          if (n * 16 + lq * 4 + r > wave * 16 + l15) sacc[n][r] = -1e30f;
    }

    // tile max for this lane's 16 k-values, reduced across lq-replicas
    float mx = -1e30f;
#pragma unroll
    for (int n = 0; n < 4; ++n)
#pragma unroll
      for (int r = 0; r < 4; ++r) mx = fmaxf(mx, sacc[n][r]);
    mx = fmaxf(mx, __shfl_xor(mx, 16));
    mx = fmaxf(mx, __shfl_xor(mx, 32));

    if (__any(mx > m_run)) {  // rescale path (rare after early tiles)
      float mnew = fmaxf(m_run, mx);
      float corr = exp2f(m_run - mnew);
      l_part *= corr;
      m_run = mnew;
      float corr4[4];
#pragma unroll
      for (int r = 0; r < 4; ++r) corr4[r] = __shfl(corr, lq * 4 + r);
#pragma unroll
      for (int nh = 0; nh < 4; ++nh)
#pragma unroll
        for (int r = 0; r < 4; ++r) oacc[nh][r] *= corr4[r];
    }

    float psum = 0.f;
#pragma unroll
    for (int n = 0; n < 4; ++n)
#pragma unroll
      for (int r = 0; r < 4; ++r) {
        float p = exp2f(sacc[n][r] - m_run);
        sacc[n][r] = p;
        psum += p;
      }
    l_part += psum;  // no cross-lane reduce here (deferred to end)

    // P^T -> per-wave LDS strip: plds[wave][q=l15][k]
#pragma unroll
    for (int n = 0; n < 4; ++n) {
      bf16x4 pk;
#pragma unroll
      for (int r = 0; r < 4; ++r) pk[r] = (bf16_t)sacc[n][r];
      *(bf16x4*)&plds[wave][l15][n * 16 + lq * 4] = pk;
    }
    bf16x8 pa[2];
    pa[0] = *(const bf16x8*)&plds[wave][l15][lq * 8];
    pa[1] = *(const bf16x8*)&plds[wave][l15][32 + lq * 8];

    __builtin_amdgcn_s_setprio(1);
#pragma unroll
    for (int nh = 0; nh < 4; ++nh)
#pragma unroll
      for (int k0 = 0; k0 < 2; ++k0)
        oacc[nh] = __builtin_amdgcn_mfma_f32_16x16x32_bf16(pa[k0], vf[nh][k0], oacc[nh], 0, 0, 0);
    __builtin_amdgcn_s_setprio(0);
  }

  // final l: sum the 4 lq-replica partials (distinct k-slices)
  float l_tot = l_part + __shfl_xor(l_part, 16);
  l_tot += __shfl_xor(l_tot, 32);

  // write partials
  const size_t prow = (size_t)bid * 64 + wave * 16;
#pragma unroll
  for (int r = 0; r < 4; ++r)
#pragma unroll
    for (int nh = 0; nh < 4; ++nh)
      opart[(prow + lq * 4 + r) * 64 + nh * 16 + l15] = (bf16_t)oacc[nh][r];
  if (lq == 0) {
    ml[(prow + l15) * 2 + 0] = m_run;
    ml[(prow + l15) * 2 + 1] = l_tot;
  }
}

// ---------------------------------------------------------------------------
// Kernel 3b: combine 8 kv-chunk partials per (b, qi). Grid 1024 =
// (cid<<2)|rq; block 256: thread -> row = rq*16 + (t>>4), cols (t&15)*4.
// ---------------------------------------------------------------------------
__global__ __launch_bounds__(256) void attn_combine(
    const bf16_t* __restrict__ opart, const float* __restrict__ ml,
    float* __restrict__ out) {
  const int bid = blockIdx.x;
  const int cid = bid >> 2;           // (b<<5)|qi
  const int rq  = bid & 3;
  const int b   = cid >> 5;
  const int qi  = cid & 31;
  const int row = rq * 16 + (threadIdx.x >> 4);
  const int c4  = (threadIdx.x & 15) * 4;

  float o0 = 0.f, o1 = 0.f, o2 = 0.f, o3 = 0.f;
  float M = -1e30f, L = 0.f;
#pragma unroll
  for (int s = 0; s < 8; ++s) {
    const size_t prow = (size_t)(cid * 8 + s) * 64 + row;
    float ms = ml[prow * 2 + 0];
    float ls = ml[prow * 2 + 1];
    float Mn = fmaxf(M, ms);
    float a  = exp2f(M - Mn);
    float bs = exp2f(ms - Mn);
    bf16x4 ov = *(const bf16x4*)(opart + prow * 64 + c4);
    o0 = o0 * a + (float)ov[0] * bs;
    o1 = o1 * a + (float)ov[1] * bs;
    o2 = o2 * a + (float)ov[2] * bs;
    o3 = o3 * a + (float)ov[3] * bs;
    L = L * a + ls * bs;
    M = Mn;
  }
  float inv = 1.0f / L;
  float4 v = {o0 * inv, o1 * inv, o2 * inv, o3 * inv};
  *(float4*)(out + ((size_t)b * T_ + qi * 64 + row) * H_ + c4) = v;
}

// ---------------------------------------------------------------------------
extern "C" void kernel_launch(void* const* d_in, const int* in_sizes, int n_in,
                              void* d_out, int out_size, void* d_ws, size_t ws_size,
                              hipStream_t stream) {
  const float* x  = (const float*)d_in[0];
  const float* Wq = (const float*)d_in[1];
  const float* Wk = (const float*)d_in[2];
  const float* Wv = (const float*)d_in[3];

  char* ws = (char*)d_ws;
  bf16_t* Wt   = (bf16_t*)(ws);                     // 384 KB
  bf16_t* qb   = (bf16_t*)(ws + (1u << 20));        // 2 MB (q * QSCALE)
  bf16_t* kb   = (bf16_t*)(ws + 3u * (1u << 20));   // 2 MB
  bf16_t* vt   = (bf16_t*)(ws + 5u * (1u << 20));   // 2 MB (v transposed)
  bf16_t* opart = (bf16_t*)(ws + 8u * (1u << 20));  // 16.8 MB (2048*64*64 bf16)
  float*  mlbuf = (float*)(ws + 25u * (1u << 20));  // 1 MB
  float*  outp  = (float*)d_out;

  hipLaunchKernelGGL(wprep_kernel, dim3(48), dim3(256), 0, stream, Wq, Wk, Wv, Wt);
  hipLaunchKernelGGL(qkv_kernel, dim3(512), dim3(256), 0, stream, x, Wt, qb, kb, vt);
  hipLaunchKernelGGL(attn_partial, dim3(2048), dim3(256), 0, stream, qb, kb, vt, opart, mlbuf);
  hipLaunchKernelGGL(attn_combine, dim3(1024), dim3(256), 0, stream, opart, mlbuf, outp);
}

// Round 8
// 90.935 us; speedup vs baseline: 1.5709x; 1.1408x over previous
//
#include <hip/hip_runtime.h>
#include <hip/hip_bf16.h>

typedef __bf16 bf16_t;
typedef __attribute__((ext_vector_type(4))) __bf16 bf16x4;
typedef __attribute__((ext_vector_type(8))) __bf16 bf16x8;
typedef __attribute__((ext_vector_type(4))) float f32x4;

#define B_ 8
#define T_ 2048
#define C_ 1024
#define H_ 64

// q-scale: H^-0.5 * log2(e)  (softmax computed in exp2 domain)
#define QSCALE 0.18033688f

// async global->LDS, 16B per lane. LDS dest = wave-uniform base + lane*16.
__device__ __forceinline__ void dma16(const bf16_t* g, bf16_t* l) {
  __builtin_amdgcn_global_load_lds(
      (const __attribute__((address_space(1))) void*)g,
      (__attribute__((address_space(3))) void*)l, 16, 0, 0);
}

// ---------------------------------------------------------------------------
// Kernel 1: convert + transpose weights -> Wt[w][h][k] bf16 (w: 0=q,1=k,2=v)
// ---------------------------------------------------------------------------
__global__ __launch_bounds__(256) void wprep_kernel(
    const float* __restrict__ Wq, const float* __restrict__ Wk,
    const float* __restrict__ Wv, bf16_t* __restrict__ Wt) {
  __shared__ float tile[64][68];
  const int t  = threadIdx.x;
  const int w  = blockIdx.x >> 4;
  const int k0 = (blockIdx.x & 15) * 64;
  const float* W = (w == 0) ? Wq : ((w == 1) ? Wk : Wv);

#pragma unroll
  for (int i = 0; i < 4; ++i) {
    int kl  = (t >> 4) + 16 * i;
    int col = (t & 15) * 4;
    float4 u = *(const float4*)(W + (size_t)(k0 + kl) * H_ + col);
    tile[kl][col + 0] = u.x; tile[kl][col + 1] = u.y;
    tile[kl][col + 2] = u.z; tile[kl][col + 3] = u.w;
  }
  __syncthreads();
#pragma unroll
  for (int i = 0; i < 4; ++i) {
    int h  = (t >> 4) + 16 * i;
    int kl = (t & 15) * 4;
    bf16x4 v;
    v[0] = (bf16_t)tile[kl + 0][h]; v[1] = (bf16_t)tile[kl + 1][h];
    v[2] = (bf16_t)tile[kl + 2][h]; v[3] = (bf16_t)tile[kl + 3][h];
    *(bf16x4*)(Wt + (size_t)w * 65536 + (size_t)h * C_ + k0 + kl) = v;
  }
}

// ---------------------------------------------------------------------------
// Kernel 2: QKV projection v6. BM=16, grid 1024 (4 blocks/CU, 16 waves/CU).
// 4-buffer XOR-swizzled LDS pipeline for x (issue at p, ds_write p+2,
// consume p+3). B-frags register-prefetched 1 phase (L2-resident Wt).
// K and V are written in FRAGMENT-TILE order (8KB per 64-token tile) so the
// attention kernel can DMA them linearly into LDS and ds_read conflict-free:
//   K tile elem [n*1024 + k0*512 + lq*128 + l15*8 + e]
//     = K[tok=tile*64+n*16+l15][h=k0*32+lq*8+e]
//   V tile elem [nh*1024 + k0*512 + lq*128 + l15*8 + e]
//     = V^T[h=nh*16+l15][tok_local=k0*32+lq*8+e]
// ---------------------------------------------------------------------------
__global__ __launch_bounds__(256) void qkv_kernel(
    const float* __restrict__ x, const bf16_t* __restrict__ Wt,
    bf16_t* __restrict__ qb, bf16_t* __restrict__ kb2, bf16_t* __restrict__ vt2) {
  __shared__ __align__(16) char xs[4][4096];  // 4 bufs x 16 rows x 256B
  const int tid  = threadIdx.x;
  const int wave = tid >> 6;
  const int lane = tid & 63;
  const int l15  = lane & 15;
  const int lq   = lane >> 4;
  const int row0 = blockIdx.x * 16;

  int wsel_[3], h_[3];
  const bf16_t* bp[3];
#pragma unroll
  for (int j = 0; j < 3; ++j) {
    int col  = wave * 48 + j * 16 + l15;
    wsel_[j] = col >> 6;
    h_[j]    = col & 63;
    bp[j] = Wt + (size_t)(wsel_[j] * 64 + h_[j]) * C_ + lq * 8;
  }

  // staging: 256 threads cover 16 rows x 64 floats per phase (16B/thread)
  const int srow = tid >> 4;
  const int fg   = tid & 15;
  const float* src = x + (size_t)(row0 + srow) * C_ + fg * 4;
  const int ssw = (srow & 7) << 4;
  const int wb  = srow * 256 + ((fg * 16) ^ ssw);
  const int rsw = (l15 & 7) << 4;

  f32x4 acc[3];
#pragma unroll
  for (int j = 0; j < 3; ++j) acc[j] = (f32x4){0.f, 0.f, 0.f, 0.f};

  float4 sA[2];
  bf16x8 bfr[2][2][3];

  {
    float4 t0 = *(const float4*)(src);
    *(float4*)(&xs[0][0] + wb) = t0;
  }
  sA[1] = *(const float4*)(src + 64);
  sA[0] = *(const float4*)(src + 128);
#pragma unroll
  for (int ks = 0; ks < 2; ++ks)
#pragma unroll
    for (int j = 0; j < 3; ++j) bfr[0][ks][j] = *(const bf16x8*)(bp[j] + ks * 32);
  __syncthreads();

#pragma unroll
  for (int p = 0; p < 16; ++p) {
    if (p + 1 < 16) {
#pragma unroll
      for (int ks = 0; ks < 2; ++ks)
#pragma unroll
        for (int j = 0; j < 3; ++j)
          bfr[(p + 1) & 1][ks][j] = *(const bf16x8*)(bp[j] + (p + 1) * 64 + ks * 32);
    }

    const char* bufc = &xs[p & 3][0];
    bf16x8 af[2];
#pragma unroll
    for (int ks = 0; ks < 2; ++ks) {
      f32x4 a0 = *(const f32x4*)(bufc + l15 * 256 + ((ks * 128 + lq * 32) ^ rsw));
      f32x4 a1 = *(const f32x4*)(bufc + l15 * 256 + ((ks * 128 + lq * 32 + 16) ^ rsw));
      bf16x8 a;
      a[0] = (bf16_t)a0[0]; a[1] = (bf16_t)a0[1]; a[2] = (bf16_t)a0[2]; a[3] = (bf16_t)a0[3];
      a[4] = (bf16_t)a1[0]; a[5] = (bf16_t)a1[1]; a[6] = (bf16_t)a1[2]; a[7] = (bf16_t)a1[3];
      af[ks] = a;
    }
    __builtin_amdgcn_s_setprio(1);
#pragma unroll
    for (int ks = 0; ks < 2; ++ks)
#pragma unroll
      for (int j = 0; j < 3; ++j)
        acc[j] = __builtin_amdgcn_mfma_f32_16x16x32_bf16(af[ks], bfr[p & 1][ks][j], acc[j], 0, 0, 0);
    __builtin_amdgcn_s_setprio(0);

    if (p + 1 < 16) {
      *(float4*)(&xs[(p + 1) & 3][0] + wb) = sA[(p + 1) & 1];
    }
    if (p + 3 < 16) {
      sA[(p + 1) & 1] = *(const float4*)(src + (p + 3) * 64);
    }
    __syncthreads();
  }

  // epilogue: q row-major*QSCALE; K/V in fragment-tile order
#pragma unroll
  for (int j = 0; j < 3; ++j)
#pragma unroll
    for (int r = 0; r < 4; ++r) {
      int mm  = row0 + lq * 4 + r;
      float v = acc[j][r];
      int h   = h_[j];
      if (wsel_[j] == 0) {
        qb[(size_t)mm * H_ + h] = (bf16_t)(v * QSCALE);
      } else {
        int bb = mm >> 11, t = mm & 2047;
        int tile = t >> 6;
        size_t base = ((size_t)bb * 32 + tile) << 12;
        if (wsel_[j] == 1) {
          int n = (t >> 4) & 3, l15k = t & 15;
          int k0 = h >> 5, lqk = (h >> 3) & 3, e = h & 7;
          kb2[base + n * 1024 + k0 * 512 + lqk * 128 + l15k * 8 + e] = (bf16_t)v;
        } else {
          int tl = t & 63;
          int k0 = tl >> 5, lqv = (tl >> 3) & 3, ev = tl & 7;
          int nh = h >> 4, l15v = h & 15;
          vt2[base + nh * 1024 + k0 * 512 + lqv * 128 + l15v * 8 + ev] = (bf16_t)v;
        }
      }
    }
}

// ---------------------------------------------------------------------------
// Kernel 3a: causal flash attention PARTIALS, split-4, LDS-shared K/V.
// Grid 1024 = (b<<7)|(qi<<2)|ch. Block = 256 threads = 4 waves (rg = wave).
// Per kv-tile: all 4 waves DMA tile t+1 (global_load_lds, fragment-ordered
// source -> linear LDS), compute tile t from LDS (ds_read_b128, conflict-
// free), one __syncthreads (drains vmcnt) per tile. K/V loaded once per
// block instead of once per wave.
// ---------------------------------------------------------------------------
__global__ __launch_bounds__(256) void attn_partial(
    const bf16_t* __restrict__ qb, const bf16_t* __restrict__ kb2,
    const bf16_t* __restrict__ vt2, bf16_t* __restrict__ opart,
    float* __restrict__ ml) {
  __shared__ bf16_t kvlds[2][8192];   // [buf][ K:0..4095 | V:4096..8191 ]
  __shared__ bf16_t plds[4][16][72];
  const int wave = threadIdx.x >> 6;  // = rg
  const int lane = threadIdx.x & 63;
  const int l15  = lane & 15;
  const int lq   = lane >> 4;
  const int bid  = blockIdx.x;
  const int b    = bid >> 7;
  const int qi   = (bid >> 2) & 31;
  const int ch   = bid & 3;
  const bf16_t* qB = qb + (size_t)b * T_ * H_;
  const int rowbase = qi * 64 + wave * 16;

  bf16x8 qf[2];
#pragma unroll
  for (int k0 = 0; k0 < 2; ++k0)
    qf[k0] = *(const bf16x8*)(qB + (size_t)(rowbase + l15) * H_ + k0 * 32 + lq * 8);

  float m_run = -1e30f;   // per-lane q-row = rowbase + l15 (log2 domain)
  float l_part = 0.f;     // per-lane partial sum (this lane's k-slice)
  f32x4 oacc[4];
#pragma unroll
  for (int nh = 0; nh < 4; ++nh) oacc[nh] = (f32x4){0.f, 0.f, 0.f, 0.f};

  const int nt = (qi >= ch) ? ((qi - ch) >> 2) + 1 : 0;
  const size_t tb = ((size_t)b * 32) << 12;

#define STAGE(KT, BUF)                                                        \
  {                                                                           \
    const bf16_t* kg = kb2 + tb + ((size_t)(KT) << 12) + wave * 1024 + lane * 8; \
    const bf16_t* vg = vt2 + tb + ((size_t)(KT) << 12) + wave * 1024 + lane * 8; \
    bf16_t* kl = &kvlds[BUF][wave * 1024];                                    \
    bf16_t* vl = &kvlds[BUF][4096 + wave * 1024];                             \
    dma16(kg, kl);        dma16(kg + 512, kl + 512);                          \
    dma16(vg, vl);        dma16(vg + 512, vl + 512);                          \
  }

  if (nt > 0) STAGE(ch, 0);
  __syncthreads();  // drains vmcnt -> tile0 resident

  int kt = ch;
  for (int it = 0; it < nt; ++it, kt += 4) {
    const int buf = it & 1;
    if (it + 1 < nt) STAGE(kt + 4, buf ^ 1);  // prefetch flies under compute

    const bf16_t* klp = &kvlds[buf][0];
    const bf16_t* vlp = &kvlds[buf][4096];

    bf16x8 kf[4][2];
#pragma unroll
    for (int n = 0; n < 4; ++n)
#pragma unroll
      for (int k0 = 0; k0 < 2; ++k0)
        kf[n][k0] = *(const bf16x8*)(klp + n * 1024 + k0 * 512 + lq * 128 + l15 * 8);

    // S^T tile: sacc[n] row = k (n*16+lq*4+r), col = q (l15)
    f32x4 sacc[4];
#pragma unroll
    for (int n = 0; n < 4; ++n) sacc[n] = (f32x4){0.f, 0.f, 0.f, 0.f};
    __builtin_amdgcn_s_setprio(1);
#pragma unroll
    for (int n = 0; n < 4; ++n)
#pragma unroll
      for (int k0 = 0; k0 < 2; ++k0)
        sacc[n] = __builtin_amdgcn_mfma_f32_16x16x32_bf16(kf[n][k0], qf[k0], sacc[n], 0, 0, 0);
    __builtin_amdgcn_s_setprio(0);

    bf16x8 vf[4][2];
#pragma unroll
    for (int nh = 0; nh < 4; ++nh)
#pragma unroll
      for (int k0 = 0; k0 < 2; ++k0)
        vf[nh][k0] = *(const bf16x8*)(vlp + nh * 1024 + k0 * 512 + lq * 128 + l15 * 8);

    if (kt == qi) {  // diagonal tile: mask k_local > q_local
#pragma unroll
      for (int n = 0; n < 4; ++n)
#pragma unroll
        for (int r = 0; r < 4; ++r)
          if (n * 16 + lq * 4 + r > wave * 16 + l15) sacc[n][r] = -1e30f;
    }

    // in-register softmax: lane owns q-col l15 (16 k-values in-register)
    float mx = -1e30f;
#pragma unroll
    for (int n = 0; n < 4; ++n)
#pragma unroll
      for (int r = 0; r < 4; ++r) mx = fmaxf(mx, sacc[n][r]);
    mx = fmaxf(mx, __shfl_xor(mx, 16));
    mx = fmaxf(mx, __shfl_xor(mx, 32));

    if (__any(mx > m_run)) {  // defer-rescale
      float mnew = fmaxf(m_run, mx);
      float corr = exp2f(m_run - mnew);
      l_part *= corr;
      m_run = mnew;
      float corr4[4];
#pragma unroll
      for (int r = 0; r < 4; ++r) corr4[r] = __shfl(corr, lq * 4 + r);
#pragma unroll
      for (int nh = 0; nh < 4; ++nh)
#pragma unroll
        for (int r = 0; r < 4; ++r) oacc[nh][r] *= corr4[r];
    }

    float psum = 0.f;
#pragma unroll
    for (int n = 0; n < 4; ++n)
#pragma unroll
      for (int r = 0; r < 4; ++r) {
        float p = exp2f(sacc[n][r] - m_run);
        sacc[n][r] = p;
        psum += p;
      }
    l_part += psum;  // cross-lane reduce deferred to end

    // P^T -> per-wave LDS strip: plds[wave][q=l15][k]
#pragma unroll
    for (int n = 0; n < 4; ++n) {
      bf16x4 pk;
#pragma unroll
      for (int r = 0; r < 4; ++r) pk[r] = (bf16_t)sacc[n][r];
      *(bf16x4*)&plds[wave][l15][n * 16 + lq * 4] = pk;
    }
    bf16x8 pa[2];
    pa[0] = *(const bf16x8*)&plds[wave][l15][lq * 8];
    pa[1] = *(const bf16x8*)&plds[wave][l15][32 + lq * 8];

    __builtin_amdgcn_s_setprio(1);
#pragma unroll
    for (int nh = 0; nh < 4; ++nh)
#pragma unroll
      for (int k0 = 0; k0 < 2; ++k0)
        oacc[nh] = __builtin_amdgcn_mfma_f32_16x16x32_bf16(pa[k0], vf[nh][k0], oacc[nh], 0, 0, 0);
    __builtin_amdgcn_s_setprio(0);

    __syncthreads();  // drains prefetch vmcnt; all waves done with buf
  }
#undef STAGE

  // final l: sum the 4 lq-replica partials (distinct k-slices)
  float l_tot = l_part + __shfl_xor(l_part, 16);
  l_tot += __shfl_xor(l_tot, 32);

  const size_t prow = (size_t)bid * 64 + wave * 16;
#pragma unroll
  for (int r = 0; r < 4; ++r)
#pragma unroll
    for (int nh = 0; nh < 4; ++nh)
      opart[(prow + lq * 4 + r) * 64 + nh * 16 + l15] = (bf16_t)oacc[nh][r];
  if (lq == 0) {
    ml[(prow + l15) * 2 + 0] = m_run;
    ml[(prow + l15) * 2 + 1] = l_tot;
  }
}

// ---------------------------------------------------------------------------
// Kernel 3b: combine 4 kv-chunk partials per (b, qi). Grid 1024 =
// (cid<<2)|rq; block 256: thread -> row = rq*16 + (t>>4), cols (t&15)*4.
// ---------------------------------------------------------------------------
__global__ __launch_bounds__(256) void attn_combine(
    const bf16_t* __restrict__ opart, const float* __restrict__ ml,
    float* __restrict__ out) {
  const int bid = blockIdx.x;
  const int cid = bid >> 2;           // (b<<5)|qi
  const int rq  = bid & 3;
  const int b   = cid >> 5;
  const int qi  = cid & 31;
  const int row = rq * 16 + (threadIdx.x >> 4);
  const int c4  = (threadIdx.x & 15) * 4;

  float o0 = 0.f, o1 = 0.f, o2 = 0.f, o3 = 0.f;
  float M = -1e30f, L = 0.f;
#pragma unroll
  for (int s = 0; s < 4; ++s) {
    const size_t prow = (size_t)(cid * 4 + s) * 64 + row;
    float ms = ml[prow * 2 + 0];
    float ls = ml[prow * 2 + 1];
    float Mn = fmaxf(M, ms);
    float a  = exp2f(M - Mn);
    float bs = exp2f(ms - Mn);
    bf16x4 ov = *(const bf16x4*)(opart + prow * 64 + c4);
    o0 = o0 * a + (float)ov[0] * bs;
    o1 = o1 * a + (float)ov[1] * bs;
    o2 = o2 * a + (float)ov[2] * bs;
    o3 = o3 * a + (float)ov[3] * bs;
    L = L * a + ls * bs;
    M = Mn;
  }
  float inv = 1.0f / L;
  float4 v = {o0 * inv, o1 * inv, o2 * inv, o3 * inv};
  *(float4*)(out + ((size_t)b * T_ + qi * 64 + row) * H_ + c4) = v;
}

// ---------------------------------------------------------------------------
extern "C" void kernel_launch(void* const* d_in, const int* in_sizes, int n_in,
                              void* d_out, int out_size, void* d_ws, size_t ws_size,
                              hipStream_t stream) {
  const float* x  = (const float*)d_in[0];
  const float* Wq = (const float*)d_in[1];
  const float* Wk = (const float*)d_in[2];
  const float* Wv = (const float*)d_in[3];

  char* ws = (char*)d_ws;
  bf16_t* Wt    = (bf16_t*)(ws);                     // 384 KB
  bf16_t* qb    = (bf16_t*)(ws + (1u << 20));        // 2 MB (q * QSCALE)
  bf16_t* kb2   = (bf16_t*)(ws + 3u * (1u << 20));   // 2 MB (frag-tile order)
  bf16_t* vt2   = (bf16_t*)(ws + 5u * (1u << 20));   // 2 MB (frag-tile order)
  bf16_t* opart = (bf16_t*)(ws + 8u * (1u << 20));   // 8 MB (1024*64*64 bf16)
  float*  mlbuf = (float*)(ws + 17u * (1u << 20));   // 512 KB
  float*  outp  = (float*)d_out;

  hipLaunchKernelGGL(wprep_kernel, dim3(48), dim3(256), 0, stream, Wq, Wk, Wv, Wt);
  hipLaunchKernelGGL(qkv_kernel, dim3(1024), dim3(256), 0, stream, x, Wt, qb, kb2, vt2);
  hipLaunchKernelGGL(attn_partial, dim3(1024), dim3(256), 0, stream, qb, kb2, vt2, opart, mlbuf);
  hipLaunchKernelGGL(attn_combine, dim3(1024), dim3(256), 0, stream, opart, mlbuf, outp);
}

// Round 9
// 60.989 us; speedup vs baseline: 2.3423x; 1.4910x over previous
//
#include <hip/hip_runtime.h>
#include <hip/hip_bf16.h>

typedef __bf16 bf16_t;
typedef __attribute__((ext_vector_type(4))) __bf16 bf16x4;
typedef __attribute__((ext_vector_type(8))) __bf16 bf16x8;
typedef __attribute__((ext_vector_type(4))) float f32x4;

#define B_ 8
#define T_ 2048
#define C_ 1024
#define H_ 64

// q-scale: H^-0.5 * log2(e)  (softmax computed in exp2 domain)
#define QSCALE 0.18033688f

// async global->LDS, 16B per lane. LDS dest = wave-uniform base + lane*16.
__device__ __forceinline__ void dma16(const void* g, void* l) {
  __builtin_amdgcn_global_load_lds(
      (const __attribute__((address_space(1))) void*)g,
      (__attribute__((address_space(3))) void*)l, 16, 0, 0);
}

// ---------------------------------------------------------------------------
// Kernel 1: convert + transpose weights -> Wt[w][h][k] bf16 (w: 0=q,1=k,2=v)
// ---------------------------------------------------------------------------
__global__ __launch_bounds__(256) void wprep_kernel(
    const float* __restrict__ Wq, const float* __restrict__ Wk,
    const float* __restrict__ Wv, bf16_t* __restrict__ Wt) {
  __shared__ float tile[64][68];
  const int t  = threadIdx.x;
  const int w  = blockIdx.x >> 4;
  const int k0 = (blockIdx.x & 15) * 64;
  const float* W = (w == 0) ? Wq : ((w == 1) ? Wk : Wv);

#pragma unroll
  for (int i = 0; i < 4; ++i) {
    int kl  = (t >> 4) + 16 * i;
    int col = (t & 15) * 4;
    float4 u = *(const float4*)(W + (size_t)(k0 + kl) * H_ + col);
    tile[kl][col + 0] = u.x; tile[kl][col + 1] = u.y;
    tile[kl][col + 2] = u.z; tile[kl][col + 3] = u.w;
  }
  __syncthreads();
#pragma unroll
  for (int i = 0; i < 4; ++i) {
    int h  = (t >> 4) + 16 * i;
    int kl = (t & 15) * 4;
    bf16x4 v;
    v[0] = (bf16_t)tile[kl + 0][h]; v[1] = (bf16_t)tile[kl + 1][h];
    v[2] = (bf16_t)tile[kl + 2][h]; v[3] = (bf16_t)tile[kl + 3][h];
    *(bf16x4*)(Wt + (size_t)w * 65536 + (size_t)h * C_ + k0 + kl) = v;
  }
}

// ---------------------------------------------------------------------------
// Kernel 2: QKV projection v7. BM=32, grid 512 (2 blocks/CU). 4 waves;
// wave = 32 rows x 48 cols = 2x3 frags of 16x16x32 MFMA. BK=32 -> 32 phases.
// x staged via global_load_lds DMA (double-buffered [2][32][128B]):
//   - source PRE-SWIZZLED per-lane: lane fetches granule (i&7)^(row&7), so
//     linear DMA leaves LDS XOR-swizzled; reads apply the same involution
//     -> ds_read_b128 2-way (free) instead of 16-way.
//   - DMA for phase p+1 issued at TOP of phase p (flies under compute).
// Wt B-frags register-prefetched dist-1 (L2-resident).
// K/V written in FRAGMENT-TILE order (8KB per 64-token tile) for attn DMA:
//   K tile elem [n*1024 + k0*512 + lq*128 + l15*8 + e] = K[tile*64+n*16+l15][k0*32+lq*8+e]
//   V tile elem [nh*1024 + k0*512 + lq*128 + l15*8 + e] = V^T[nh*16+l15][k0*32+lq*8+e]
// ---------------------------------------------------------------------------
__global__ __launch_bounds__(256) void qkv_kernel(
    const float* __restrict__ x, const bf16_t* __restrict__ Wt,
    bf16_t* __restrict__ qb, bf16_t* __restrict__ kb2, bf16_t* __restrict__ vt2) {
  __shared__ __align__(16) char xs[2][4096];  // [buf][32 rows x 128B]
  const int tid  = threadIdx.x;
  const int wave = tid >> 6;
  const int lane = tid & 63;
  const int l15  = lane & 15;
  const int lq   = lane >> 4;
  const int row0 = blockIdx.x * 32;

  int wsel_[3], h_[3];
  const bf16_t* bp[3];
#pragma unroll
  for (int j = 0; j < 3; ++j) {
    int col  = wave * 48 + j * 16 + l15;
    wsel_[j] = col >> 6;
    h_[j]    = col & 63;
    bp[j] = Wt + (size_t)(wsel_[j] * 64 + h_[j]) * C_ + lq * 8;
  }

  // DMA mapping: wave w covers rows 8w..8w+7; lane i -> row 8w+(i>>3),
  // 16B granule (i&7), source granule pre-swizzled by ^(row&7).
  const int drow = wave * 8 + (lane >> 3);
  const int dg   = (lane & 7) ^ (drow & 7);
  const float* dsrc = x + (size_t)(row0 + drow) * C_ + dg * 4;
  char* dst0 = &xs[0][wave * 1024];  // wave-uniform base; lane offset = lane*16
  char* dst1 = &xs[1][wave * 1024];

  // read swizzle: row = m*16+l15 -> s = l15&7 (16 = 0 mod 8)
  const int rs = l15 & 7;
  const int g0 = ((2 * lq) ^ rs) * 16;
  const int g1 = ((2 * lq + 1) ^ rs) * 16;

  f32x4 acc[2][3];
#pragma unroll
  for (int m = 0; m < 2; ++m)
#pragma unroll
    for (int j = 0; j < 3; ++j) acc[m][j] = (f32x4){0.f, 0.f, 0.f, 0.f};

  bf16x8 bcur[3], bnext[3];

  // prologue: DMA phase 0, preload B(0)
  dma16(dsrc, dst0);
#pragma unroll
  for (int j = 0; j < 3; ++j) bcur[j] = *(const bf16x8*)bp[j];
  __syncthreads();

  for (int p = 0; p < 32; ++p) {
    // a) issue DMA for phase p+1 (lands by this phase's end barrier)
    if (p + 1 < 32) dma16(dsrc + (p + 1) * 32, ((p + 1) & 1) ? dst1 : dst0);

    // b) prefetch next B frags (L2)
    if (p + 1 < 32) {
#pragma unroll
      for (int j = 0; j < 3; ++j) bnext[j] = *(const bf16x8*)(bp[j] + (p + 1) * 32);
    }

    // c) A-frags from swizzled LDS + convert
    const char* bufc = &xs[p & 1][0];
    bf16x8 af[2];
#pragma unroll
    for (int m = 0; m < 2; ++m) {
      const int rbase = (m * 16 + l15) * 128;
      f32x4 a0 = *(const f32x4*)(bufc + rbase + g0);
      f32x4 a1 = *(const f32x4*)(bufc + rbase + g1);
      bf16x8 a;
      a[0] = (bf16_t)a0[0]; a[1] = (bf16_t)a0[1]; a[2] = (bf16_t)a0[2]; a[3] = (bf16_t)a0[3];
      a[4] = (bf16_t)a1[0]; a[5] = (bf16_t)a1[1]; a[6] = (bf16_t)a1[2]; a[7] = (bf16_t)a1[3];
      af[m] = a;
    }

    __builtin_amdgcn_s_setprio(1);
#pragma unroll
    for (int m = 0; m < 2; ++m)
#pragma unroll
      for (int j = 0; j < 3; ++j)
        acc[m][j] = __builtin_amdgcn_mfma_f32_16x16x32_bf16(af[m], bcur[j], acc[m][j], 0, 0, 0);
    __builtin_amdgcn_s_setprio(0);

#pragma unroll
    for (int j = 0; j < 3; ++j) bcur[j] = bnext[j];
    __syncthreads();  // drains DMA(p+1) + all waves done reading buf p&1
  }

  // epilogue: q row-major * QSCALE; K/V in fragment-tile order
#pragma unroll
  for (int m = 0; m < 2; ++m)
#pragma unroll
    for (int j = 0; j < 3; ++j)
#pragma unroll
      for (int r = 0; r < 4; ++r) {
        int mm  = row0 + m * 16 + lq * 4 + r;
        float v = acc[m][j][r];
        int h   = h_[j];
        if (wsel_[j] == 0) {
          qb[(size_t)mm * H_ + h] = (bf16_t)(v * QSCALE);
        } else {
          int bb = mm >> 11, t = mm & 2047;
          int tile = t >> 6;
          size_t base = ((size_t)bb * 32 + tile) << 12;
          if (wsel_[j] == 1) {
            int n = (t >> 4) & 3, l15k = t & 15;
            int k0 = h >> 5, lqk = (h >> 3) & 3, e = h & 7;
            kb2[base + n * 1024 + k0 * 512 + lqk * 128 + l15k * 8 + e] = (bf16_t)v;
          } else {
            int tl = t & 63;
            int k0 = tl >> 5, lqv = (tl >> 3) & 3, ev = tl & 7;
            int nh = h >> 4, l15v = h & 15;
            vt2[base + nh * 1024 + k0 * 512 + lqv * 128 + l15v * 8 + ev] = (bf16_t)v;
          }
        }
      }
}

// ---------------------------------------------------------------------------
// Kernel 3a: causal flash attention PARTIALS, split-4, LDS-shared K/V (DMA).
// Grid 1024 = (b<<7)|(qi<<2)|ch. Block = 256 threads = 4 waves (rg = wave).
// Per kv-tile: DMA tile t+1, compute tile t from LDS, one barrier per tile.
// ---------------------------------------------------------------------------
__global__ __launch_bounds__(256) void attn_partial(
    const bf16_t* __restrict__ qb, const bf16_t* __restrict__ kb2,
    const bf16_t* __restrict__ vt2, bf16_t* __restrict__ opart,
    float* __restrict__ ml) {
  __shared__ bf16_t kvlds[2][8192];   // [buf][ K:0..4095 | V:4096..8191 ]
  __shared__ bf16_t plds[4][16][72];
  const int wave = threadIdx.x >> 6;  // = rg
  const int lane = threadIdx.x & 63;
  const int l15  = lane & 15;
  const int lq   = lane >> 4;
  const int bid  = blockIdx.x;
  const int b    = bid >> 7;
  const int qi   = (bid >> 2) & 31;
  const int ch   = bid & 3;
  const bf16_t* qB = qb + (size_t)b * T_ * H_;
  const int rowbase = qi * 64 + wave * 16;

  bf16x8 qf[2];
#pragma unroll
  for (int k0 = 0; k0 < 2; ++k0)
    qf[k0] = *(const bf16x8*)(qB + (size_t)(rowbase + l15) * H_ + k0 * 32 + lq * 8);

  float m_run = -1e30f;   // per-lane q-row = rowbase + l15 (log2 domain)
  float l_part = 0.f;     // per-lane partial sum (this lane's k-slice)
  f32x4 oacc[4];
#pragma unroll
  for (int nh = 0; nh < 4; ++nh) oacc[nh] = (f32x4){0.f, 0.f, 0.f, 0.f};

  const int nt = (qi >= ch) ? ((qi - ch) >> 2) + 1 : 0;
  const size_t tb = ((size_t)b * 32) << 12;

#define STAGE(KT, BUF)                                                        \
  {                                                                           \
    const bf16_t* kg = kb2 + tb + ((size_t)(KT) << 12) + wave * 1024 + lane * 8; \
    const bf16_t* vg = vt2 + tb + ((size_t)(KT) << 12) + wave * 1024 + lane * 8; \
    bf16_t* kl = &kvlds[BUF][wave * 1024];                                    \
    bf16_t* vl = &kvlds[BUF][4096 + wave * 1024];                             \
    dma16(kg, kl);        dma16(kg + 512, kl + 512);                          \
    dma16(vg, vl);        dma16(vg + 512, vl + 512);                          \
  }

  if (nt > 0) STAGE(ch, 0);
  __syncthreads();  // drains vmcnt -> tile0 resident

  int kt = ch;
  for (int it = 0; it < nt; ++it, kt += 4) {
    const int buf = it & 1;
    if (it + 1 < nt) STAGE(kt + 4, buf ^ 1);  // prefetch flies under compute

    const bf16_t* klp = &kvlds[buf][0];
    const bf16_t* vlp = &kvlds[buf][4096];

    bf16x8 kf[4][2];
#pragma unroll
    for (int n = 0; n < 4; ++n)
#pragma unroll
      for (int k0 = 0; k0 < 2; ++k0)
        kf[n][k0] = *(const bf16x8*)(klp + n * 1024 + k0 * 512 + lq * 128 + l15 * 8);

    // S^T tile: sacc[n] row = k (n*16+lq*4+r), col = q (l15)
    f32x4 sacc[4];
#pragma unroll
    for (int n = 0; n < 4; ++n) sacc[n] = (f32x4){0.f, 0.f, 0.f, 0.f};
    __builtin_amdgcn_s_setprio(1);
#pragma unroll
    for (int n = 0; n < 4; ++n)
#pragma unroll
      for (int k0 = 0; k0 < 2; ++k0)
        sacc[n] = __builtin_amdgcn_mfma_f32_16x16x32_bf16(kf[n][k0], qf[k0], sacc[n], 0, 0, 0);
    __builtin_amdgcn_s_setprio(0);

    bf16x8 vf[4][2];
#pragma unroll
    for (int nh = 0; nh < 4; ++nh)
#pragma unroll
      for (int k0 = 0; k0 < 2; ++k0)
        vf[nh][k0] = *(const bf16x8*)(vlp + nh * 1024 + k0 * 512 + lq * 128 + l15 * 8);

    if (kt == qi) {  // diagonal tile: mask k_local > q_local
#pragma unroll
      for (int n = 0; n < 4; ++n)
#pragma unroll
        for (int r = 0; r < 4; ++r)
          if (n * 16 + lq * 4 + r > wave * 16 + l15) sacc[n][r] = -1e30f;
    }

    // in-register softmax: lane owns q-col l15 (16 k-values in-register)
    float mx = -1e30f;
#pragma unroll
    for (int n = 0; n < 4; ++n)
#pragma unroll
      for (int r = 0; r < 4; ++r) mx = fmaxf(mx, sacc[n][r]);
    mx = fmaxf(mx, __shfl_xor(mx, 16));
    mx = fmaxf(mx, __shfl_xor(mx, 32));

    if (__any(mx > m_run)) {  // defer-rescale
      float mnew = fmaxf(m_run, mx);
      float corr = exp2f(m_run - mnew);
      l_part *= corr;
      m_run = mnew;
      float corr4[4];
#pragma unroll
      for (int r = 0; r < 4; ++r) corr4[r] = __shfl(corr, lq * 4 + r);
#pragma unroll
      for (int nh = 0; nh < 4; ++nh)
#pragma unroll
        for (int r = 0; r < 4; ++r) oacc[nh][r] *= corr4[r];
    }

    float psum = 0.f;
#pragma unroll
    for (int n = 0; n < 4; ++n)
#pragma unroll
      for (int r = 0; r < 4; ++r) {
        float p = exp2f(sacc[n][r] - m_run);
        sacc[n][r] = p;
        psum += p;
      }
    l_part += psum;  // cross-lane reduce deferred to end

    // P^T -> per-wave LDS strip: plds[wave][q=l15][k]
#pragma unroll
    for (int n = 0; n < 4; ++n) {
      bf16x4 pk;
#pragma unroll
      for (int r = 0; r < 4; ++r) pk[r] = (bf16_t)sacc[n][r];
      *(bf16x4*)&plds[wave][l15][n * 16 + lq * 4] = pk;
    }
    bf16x8 pa[2];
    pa[0] = *(const bf16x8*)&plds[wave][l15][lq * 8];
    pa[1] = *(const bf16x8*)&plds[wave][l15][32 + lq * 8];

    __builtin_amdgcn_s_setprio(1);
#pragma unroll
    for (int nh = 0; nh < 4; ++nh)
#pragma unroll
      for (int k0 = 0; k0 < 2; ++k0)
        oacc[nh] = __builtin_amdgcn_mfma_f32_16x16x32_bf16(pa[k0], vf[nh][k0], oacc[nh], 0, 0, 0);
    __builtin_amdgcn_s_setprio(0);

    __syncthreads();  // drains prefetch vmcnt; all waves done with buf
  }
#undef STAGE

  // final l: sum the 4 lq-replica partials (distinct k-slices)
  float l_tot = l_part + __shfl_xor(l_part, 16);
  l_tot += __shfl_xor(l_tot, 32);

  const size_t prow = (size_t)bid * 64 + wave * 16;
#pragma unroll
  for (int r = 0; r < 4; ++r)
#pragma unroll
    for (int nh = 0; nh < 4; ++nh)
      opart[(prow + lq * 4 + r) * 64 + nh * 16 + l15] = (bf16_t)oacc[nh][r];
  if (lq == 0) {
    ml[(prow + l15) * 2 + 0] = m_run;
    ml[(prow + l15) * 2 + 1] = l_tot;
  }
}

// ---------------------------------------------------------------------------
// Kernel 3b: combine 4 kv-chunk partials per (b, qi). Grid 1024 =
// (cid<<2)|rq; block 256: thread -> row = rq*16 + (t>>4), cols (t&15)*4.
// ---------------------------------------------------------------------------
__global__ __launch_bounds__(256) void attn_combine(
    const bf16_t* __restrict__ opart, const float* __restrict__ ml,
    float* __restrict__ out) {
  const int bid = blockIdx.x;
  const int cid = bid >> 2;           // (b<<5)|qi
  const int rq  = bid & 3;
  const int b   = cid >> 5;
  const int qi  = cid & 31;
  const int row = rq * 16 + (threadIdx.x >> 4);
  const int c4  = (threadIdx.x & 15) * 4;

  float o0 = 0.f, o1 = 0.f, o2 = 0.f, o3 = 0.f;
  float M = -1e30f, L = 0.f;
#pragma unroll
  for (int s = 0; s < 4; ++s) {
    const size_t prow = (size_t)(cid * 4 + s) * 64 + row;
    float ms = ml[prow * 2 + 0];
    float ls = ml[prow * 2 + 1];
    float Mn = fmaxf(M, ms);
    float a  = exp2f(M - Mn);
    float bs = exp2f(ms - Mn);
    bf16x4 ov = *(const bf16x4*)(opart + prow * 64 + c4);
    o0 = o0 * a + (float)ov[0] * bs;
    o1 = o1 * a + (float)ov[1] * bs;
    o2 = o2 * a + (float)ov[2] * bs;
    o3 = o3 * a + (float)ov[3] * bs;
    L = L * a + ls * bs;
    M = Mn;
  }
  float inv = 1.0f / L;
  float4 v = {o0 * inv, o1 * inv, o2 * inv, o3 * inv};
  *(float4*)(out + ((size_t)b * T_ + qi * 64 + row) * H_ + c4) = v;
}

// ---------------------------------------------------------------------------
extern "C" void kernel_launch(void* const* d_in, const int* in_sizes, int n_in,
                              void* d_out, int out_size, void* d_ws, size_t ws_size,
                              hipStream_t stream) {
  const float* x  = (const float*)d_in[0];
  const float* Wq = (const float*)d_in[1];
  const float* Wk = (const float*)d_in[2];
  const float* Wv = (const float*)d_in[3];

  char* ws = (char*)d_ws;
  bf16_t* Wt    = (bf16_t*)(ws);                     // 384 KB
  bf16_t* qb    = (bf16_t*)(ws + (1u << 20));        // 2 MB (q * QSCALE)
  bf16_t* kb2   = (bf16_t*)(ws + 3u * (1u << 20));   // 2 MB (frag-tile order)
  bf16_t* vt2   = (bf16_t*)(ws + 5u * (1u << 20));   // 2 MB (frag-tile order)
  bf16_t* opart = (bf16_t*)(ws + 8u * (1u << 20));   // 8 MB (1024*64*64 bf16)
  float*  mlbuf = (float*)(ws + 17u * (1u << 20));   // 512 KB
  float*  outp  = (float*)d_out;

  hipLaunchKernelGGL(wprep_kernel, dim3(48), dim3(256), 0, stream, Wq, Wk, Wv, Wt);
  hipLaunchKernelGGL(qkv_kernel, dim3(512), dim3(256), 0, stream, x, Wt, qb, kb2, vt2);
  hipLaunchKernelGGL(attn_partial, dim3(1024), dim3(256), 0, stream, qb, kb2, vt2, opart, mlbuf);
  hipLaunchKernelGGL(attn_combine, dim3(1024), dim3(256), 0, stream, opart, mlbuf, outp);
}

// Round 10
// 59.459 us; speedup vs baseline: 2.4025x; 1.0257x over previous
//
#include <hip/hip_runtime.h>
#include <hip/hip_bf16.h>

typedef __bf16 bf16_t;
typedef __attribute__((ext_vector_type(4))) __bf16 bf16x4;
typedef __attribute__((ext_vector_type(8))) __bf16 bf16x8;
typedef __attribute__((ext_vector_type(4))) float f32x4;

#define B_ 8
#define T_ 2048
#define C_ 1024
#define H_ 64

// q-scale: H^-0.5 * log2(e)  (softmax computed in exp2 domain)
#define QSCALE 0.18033688f

// async global->LDS, 16B per lane. LDS dest = wave-uniform base + lane*16.
__device__ __forceinline__ void dma16(const void* g, void* l) {
  __builtin_amdgcn_global_load_lds(
      (const __attribute__((address_space(1))) void*)g,
      (__attribute__((address_space(3))) void*)l, 16, 0, 0);
}

// ---------------------------------------------------------------------------
// Kernel 1: convert + transpose weights -> Wt[col][k] bf16 (col = wsel*64+h)
// ---------------------------------------------------------------------------
__global__ __launch_bounds__(256) void wprep_kernel(
    const float* __restrict__ Wq, const float* __restrict__ Wk,
    const float* __restrict__ Wv, bf16_t* __restrict__ Wt) {
  __shared__ float tile[64][68];
  const int t  = threadIdx.x;
  const int w  = blockIdx.x >> 4;
  const int k0 = (blockIdx.x & 15) * 64;
  const float* W = (w == 0) ? Wq : ((w == 1) ? Wk : Wv);

#pragma unroll
  for (int i = 0; i < 4; ++i) {
    int kl  = (t >> 4) + 16 * i;
    int col = (t & 15) * 4;
    float4 u = *(const float4*)(W + (size_t)(k0 + kl) * H_ + col);
    tile[kl][col + 0] = u.x; tile[kl][col + 1] = u.y;
    tile[kl][col + 2] = u.z; tile[kl][col + 3] = u.w;
  }
  __syncthreads();
#pragma unroll
  for (int i = 0; i < 4; ++i) {
    int h  = (t >> 4) + 16 * i;
    int kl = (t & 15) * 4;
    bf16x4 v;
    v[0] = (bf16_t)tile[kl + 0][h]; v[1] = (bf16_t)tile[kl + 1][h];
    v[2] = (bf16_t)tile[kl + 2][h]; v[3] = (bf16_t)tile[kl + 3][h];
    *(bf16x4*)(Wt + (size_t)w * 65536 + (size_t)h * C_ + k0 + kl) = v;
  }
}

// ---------------------------------------------------------------------------
// Kernel 2: QKV projection v8 — ALL-DMA K-loop, counted vmcnt, raw barriers.
// BM=32, grid 512 (2 blocks/CU), 4 waves; wave = 32 rows x 48 cols
// (2x3 frags), BK=32 -> 32 phases.
// Staging (per wave per phase, fixed order B,B,B,A = 4 DMA instrs):
//   B (wave's own 3 col-frags from Wt, L2-hot)  -> bufB[(p+2)%3], dist-2
//   A (x rows, HBM)                             -> bufA[(p+3)&4], dist-3
// Phase top: s_waitcnt vmcnt(5)  (forces A(p),B(p); leaves 5 newer flying)
//            raw s_barrier (NO vmcnt(0) drain)  -> collective visibility.
// No register VMEM loads in the loop => no compiler waits trap the DMAs.
// Swizzles (conflict-free per 8-lane octet):
//   A: slot (i&7)^(row&7) on source; read granule g -> slot g^(l15&7)
//   B: slot (i&3)^((i>>3)&3) on source; read granule lq -> slot lq^((l15>>1)&3)
// Tail phases issue wrapped dummy DMAs (kept: uniform vmcnt accounting).
// ---------------------------------------------------------------------------
__global__ __launch_bounds__(256) void qkv_kernel(
    const float* __restrict__ x, const bf16_t* __restrict__ Wt,
    bf16_t* __restrict__ qb, bf16_t* __restrict__ kb2, bf16_t* __restrict__ vt2) {
  __shared__ __align__(16) char xsA[4][4096];   // 32 rows x 128B
  __shared__ __align__(16) char xsB[3][12288];  // 4 waves x 3 frags x 1KB
  const int tid  = threadIdx.x;
  const int wave = tid >> 6;
  const int lane = tid & 63;
  const int l15  = lane & 15;
  const int lq   = lane >> 4;
  const int row0 = blockIdx.x * 32;

  // A-DMA source: wave w covers rows 8w..8w+7; lane i -> row 8w+(i>>3),
  // granule (i&7)^(row&7) (pre-swizzled source, linear LDS dest).
  const int drow = wave * 8 + (lane >> 3);
  const int dg   = (lane & 7) ^ (drow & 7);
  const float* asrc = x + (size_t)(row0 + drow) * C_ + dg * 4;

  // B-DMA source: frag f covers cols wave*48+f*16..+15 (Wt row == col).
  // lane i -> local row hloc=i>>2, granule (i&3)^((i>>3)&3).
  const int hloc = lane >> 2;
  const int bg   = (lane & 3) ^ ((lane >> 3) & 3);
  const bf16_t* bsrc0 = Wt + (size_t)(wave * 48 +  0 + hloc) * C_ + bg * 8;
  const bf16_t* bsrc1 = Wt + (size_t)(wave * 48 + 16 + hloc) * C_ + bg * 8;
  const bf16_t* bsrc2 = Wt + (size_t)(wave * 48 + 32 + hloc) * C_ + bg * 8;

  // per-frag output metadata
  int wsel_[3], h_[3];
#pragma unroll
  for (int j = 0; j < 3; ++j) {
    int col  = wave * 48 + j * 16 + l15;
    wsel_[j] = col >> 6;
    h_[j]    = col & 63;
  }

  // read swizzles
  const int rsA = l15 & 7;                 // A: row = m*16+l15, 16%8==0
  const int g0  = ((2 * lq) ^ rsA) * 16;
  const int g1  = ((2 * lq + 1) ^ rsA) * 16;
  const int sB  = (lq ^ ((l15 >> 1) & 3)) * 16;  // B slot byte offset

  f32x4 acc[2][3];
#pragma unroll
  for (int m = 0; m < 2; ++m)
#pragma unroll
    for (int j = 0; j < 3; ++j) acc[m][j] = (f32x4){0.f, 0.f, 0.f, 0.f};

  // prologue: A0, B0, A1, B1, A2 (9 instrs) — establishes vmcnt(5) invariant
  dma16(asrc,       &xsA[0][wave * 1024]);
  {
    char* bB = &xsB[0][wave * 3072];
    dma16(bsrc0, bB); dma16(bsrc1, bB + 1024); dma16(bsrc2, bB + 2048);
  }
  dma16(asrc + 32,  &xsA[1][wave * 1024]);
  {
    char* bB = &xsB[1][wave * 3072];
    dma16(bsrc0 + 32, bB); dma16(bsrc1 + 32, bB + 1024); dma16(bsrc2 + 32, bB + 2048);
  }
  dma16(asrc + 64,  &xsA[2][wave * 1024]);

  for (int p = 0; p < 32; ++p) {
    // wait: forces A(p), B(p) landed (5 newer ops keep flying)
    asm volatile("s_waitcnt vmcnt(5)" ::: "memory");
    __builtin_amdgcn_s_barrier();          // raw barrier: no vmcnt(0) drain
    __builtin_amdgcn_sched_barrier(0);

    // issue next batches (post-barrier: target buffers are read-free)
    {
      const int tq = (p + 2) & 31;         // B distance-2 (dummy-wraps at tail)
      char* bB = &xsB[(p + 2) % 3][wave * 3072];
      dma16(bsrc0 + tq * 32, bB);
      dma16(bsrc1 + tq * 32, bB + 1024);
      dma16(bsrc2 + tq * 32, bB + 2048);
      const int tp = (p + 3) & 31;         // A distance-3
      dma16(asrc + tp * 32, &xsA[(p + 3) & 3][wave * 1024]);
    }
    __builtin_amdgcn_sched_barrier(0);

    // compute phase p from bufA[p&3], bufB[p%3]
    const char* bufa = &xsA[p & 3][0];
    const char* bufb = &xsB[p % 3][wave * 3072];
    bf16x8 af[2];
#pragma unroll
    for (int m = 0; m < 2; ++m) {
      const int rbase = (m * 16 + l15) * 128;
      f32x4 a0 = *(const f32x4*)(bufa + rbase + g0);
      f32x4 a1 = *(const f32x4*)(bufa + rbase + g1);
      bf16x8 a;
      a[0] = (bf16_t)a0[0]; a[1] = (bf16_t)a0[1]; a[2] = (bf16_t)a0[2]; a[3] = (bf16_t)a0[3];
      a[4] = (bf16_t)a1[0]; a[5] = (bf16_t)a1[1]; a[6] = (bf16_t)a1[2]; a[7] = (bf16_t)a1[3];
      af[m] = a;
    }
    bf16x8 bfv[3];
#pragma unroll
    for (int j = 0; j < 3; ++j)
      bfv[j] = *(const bf16x8*)(bufb + j * 1024 + l15 * 64 + sB);

    __builtin_amdgcn_s_setprio(1);
#pragma unroll
    for (int m = 0; m < 2; ++m)
#pragma unroll
      for (int j = 0; j < 3; ++j)
        acc[m][j] = __builtin_amdgcn_mfma_f32_16x16x32_bf16(af[m], bfv[j], acc[m][j], 0, 0, 0);
    __builtin_amdgcn_s_setprio(0);
  }

  // drain remaining DMAs before any wave can exit (LDS dealloc hazard)
  asm volatile("s_waitcnt vmcnt(0)" ::: "memory");

  // epilogue: q row-major * QSCALE; K/V in fragment-tile order
#pragma unroll
  for (int m = 0; m < 2; ++m)
#pragma unroll
    for (int j = 0; j < 3; ++j)
#pragma unroll
      for (int r = 0; r < 4; ++r) {
        int mm  = row0 + m * 16 + lq * 4 + r;
        float v = acc[m][j][r];
        int h   = h_[j];
        if (wsel_[j] == 0) {
          qb[(size_t)mm * H_ + h] = (bf16_t)(v * QSCALE);
        } else {
          int bb = mm >> 11, t = mm & 2047;
          int tile = t >> 6;
          size_t base = ((size_t)bb * 32 + tile) << 12;
          if (wsel_[j] == 1) {
            int n = (t >> 4) & 3, l15k = t & 15;
            int k0 = h >> 5, lqk = (h >> 3) & 3, e = h & 7;
            kb2[base + n * 1024 + k0 * 512 + lqk * 128 + l15k * 8 + e] = (bf16_t)v;
          } else {
            int tl = t & 63;
            int k0 = tl >> 5, lqv = (tl >> 3) & 3, ev = tl & 7;
            int nh = h >> 4, l15v = h & 15;
            vt2[base + nh * 1024 + k0 * 512 + lqv * 128 + l15v * 8 + ev] = (bf16_t)v;
          }
        }
      }
}

// ---------------------------------------------------------------------------
// Kernel 3a: causal flash attention PARTIALS, split-4, LDS-shared K/V (DMA).
// Grid 1024 = (b<<7)|(qi<<2)|ch. Block = 256 threads = 4 waves (rg = wave).
// Per kv-tile: DMA tile t+1, compute tile t from LDS, one barrier per tile.
// ---------------------------------------------------------------------------
__global__ __launch_bounds__(256) void attn_partial(
    const bf16_t* __restrict__ qb, const bf16_t* __restrict__ kb2,
    const bf16_t* __restrict__ vt2, bf16_t* __restrict__ opart,
    float* __restrict__ ml) {
  __shared__ bf16_t kvlds[2][8192];   // [buf][ K:0..4095 | V:4096..8191 ]
  __shared__ bf16_t plds[4][16][72];
  const int wave = threadIdx.x >> 6;  // = rg
  const int lane = threadIdx.x & 63;
  const int l15  = lane & 15;
  const int lq   = lane >> 4;
  const int bid  = blockIdx.x;
  const int b    = bid >> 7;
  const int qi   = (bid >> 2) & 31;
  const int ch   = bid & 3;
  const bf16_t* qB = qb + (size_t)b * T_ * H_;
  const int rowbase = qi * 64 + wave * 16;

  bf16x8 qf[2];
#pragma unroll
  for (int k0 = 0; k0 < 2; ++k0)
    qf[k0] = *(const bf16x8*)(qB + (size_t)(rowbase + l15) * H_ + k0 * 32 + lq * 8);

  float m_run = -1e30f;   // per-lane q-row = rowbase + l15 (log2 domain)
  float l_part = 0.f;     // per-lane partial sum (this lane's k-slice)
  f32x4 oacc[4];
#pragma unroll
  for (int nh = 0; nh < 4; ++nh) oacc[nh] = (f32x4){0.f, 0.f, 0.f, 0.f};

  const int nt = (qi >= ch) ? ((qi - ch) >> 2) + 1 : 0;
  const size_t tb = ((size_t)b * 32) << 12;

#define STAGE(KT, BUF)                                                        \
  {                                                                           \
    const bf16_t* kg = kb2 + tb + ((size_t)(KT) << 12) + wave * 1024 + lane * 8; \
    const bf16_t* vg = vt2 + tb + ((size_t)(KT) << 12) + wave * 1024 + lane * 8; \
    bf16_t* kl = &kvlds[BUF][wave * 1024];                                    \
    bf16_t* vl = &kvlds[BUF][4096 + wave * 1024];                             \
    dma16(kg, kl);        dma16(kg + 512, kl + 512);                          \
    dma16(vg, vl);        dma16(vg + 512, vl + 512);                          \
  }

  if (nt > 0) STAGE(ch, 0);
  __syncthreads();  // drains vmcnt -> tile0 resident

  int kt = ch;
  for (int it = 0; it < nt; ++it, kt += 4) {
    const int buf = it & 1;
    if (it + 1 < nt) STAGE(kt + 4, buf ^ 1);  // prefetch flies under compute

    const bf16_t* klp = &kvlds[buf][0];
    const bf16_t* vlp = &kvlds[buf][4096];

    bf16x8 kf[4][2];
#pragma unroll
    for (int n = 0; n < 4; ++n)
#pragma unroll
      for (int k0 = 0; k0 < 2; ++k0)
        kf[n][k0] = *(const bf16x8*)(klp + n * 1024 + k0 * 512 + lq * 128 + l15 * 8);

    // S^T tile: sacc[n] row = k (n*16+lq*4+r), col = q (l15)
    f32x4 sacc[4];
#pragma unroll
    for (int n = 0; n < 4; ++n) sacc[n] = (f32x4){0.f, 0.f, 0.f, 0.f};
    __builtin_amdgcn_s_setprio(1);
#pragma unroll
    for (int n = 0; n < 4; ++n)
#pragma unroll
      for (int k0 = 0; k0 < 2; ++k0)
        sacc[n] = __builtin_amdgcn_mfma_f32_16x16x32_bf16(kf[n][k0], qf[k0], sacc[n], 0, 0, 0);
    __builtin_amdgcn_s_setprio(0);

    bf16x8 vf[4][2];
#pragma unroll
    for (int nh = 0; nh < 4; ++nh)
#pragma unroll
      for (int k0 = 0; k0 < 2; ++k0)
        vf[nh][k0] = *(const bf16x8*)(vlp + nh * 1024 + k0 * 512 + lq * 128 + l15 * 8);

    if (kt == qi) {  // diagonal tile: mask k_local > q_local
#pragma unroll
      for (int n = 0; n < 4; ++n)
#pragma unroll
        for (int r = 0; r < 4; ++r)
          if (n * 16 + lq * 4 + r > wave * 16 + l15) sacc[n][r] = -1e30f;
    }

    // in-register softmax: lane owns q-col l15 (16 k-values in-register)
    float mx = -1e30f;
#pragma unroll
    for (int n = 0; n < 4; ++n)
#pragma unroll
      for (int r = 0; r < 4; ++r) mx = fmaxf(mx, sacc[n][r]);
    mx = fmaxf(mx, __shfl_xor(mx, 16));
    mx = fmaxf(mx, __shfl_xor(mx, 32));

    if (__any(mx > m_run)) {  // defer-rescale
      float mnew = fmaxf(m_run, mx);
      float corr = exp2f(m_run - mnew);
      l_part *= corr;
      m_run = mnew;
      float corr4[4];
#pragma unroll
      for (int r = 0; r < 4; ++r) corr4[r] = __shfl(corr, lq * 4 + r);
#pragma unroll
      for (int nh = 0; nh < 4; ++nh)
#pragma unroll
        for (int r = 0; r < 4; ++r) oacc[nh][r] *= corr4[r];
    }

    float psum = 0.f;
#pragma unroll
    for (int n = 0; n < 4; ++n)
#pragma unroll
      for (int r = 0; r < 4; ++r) {
        float p = exp2f(sacc[n][r] - m_run);
        sacc[n][r] = p;
        psum += p;
      }
    l_part += psum;  // cross-lane reduce deferred to end

    // P^T -> per-wave LDS strip: plds[wave][q=l15][k]
#pragma unroll
    for (int n = 0; n < 4; ++n) {
      bf16x4 pk;
#pragma unroll
      for (int r = 0; r < 4; ++r) pk[r] = (bf16_t)sacc[n][r];
      *(bf16x4*)&plds[wave][l15][n * 16 + lq * 4] = pk;
    }
    bf16x8 pa[2];
    pa[0] = *(const bf16x8*)&plds[wave][l15][lq * 8];
    pa[1] = *(const bf16x8*)&plds[wave][l15][32 + lq * 8];

    __builtin_amdgcn_s_setprio(1);
#pragma unroll
    for (int nh = 0; nh < 4; ++nh)
#pragma unroll
      for (int k0 = 0; k0 < 2; ++k0)
        oacc[nh] = __builtin_amdgcn_mfma_f32_16x16x32_bf16(pa[k0], vf[nh][k0], oacc[nh], 0, 0, 0);
    __builtin_amdgcn_s_setprio(0);

    __syncthreads();  // drains prefetch vmcnt; all waves done with buf
  }
#undef STAGE

  // final l: sum the 4 lq-replica partials (distinct k-slices)
  float l_tot = l_part + __shfl_xor(l_part, 16);
  l_tot += __shfl_xor(l_tot, 32);

  const size_t prow = (size_t)bid * 64 + wave * 16;
#pragma unroll
  for (int r = 0; r < 4; ++r)
#pragma unroll
    for (int nh = 0; nh < 4; ++nh)
      opart[(prow + lq * 4 + r) * 64 + nh * 16 + l15] = (bf16_t)oacc[nh][r];
  if (lq == 0) {
    ml[(prow + l15) * 2 + 0] = m_run;
    ml[(prow + l15) * 2 + 1] = l_tot;
  }
}

// ---------------------------------------------------------------------------
// Kernel 3b: combine 4 kv-chunk partials per (b, qi). Grid 1024 =
// (cid<<2)|rq; block 256: thread -> row = rq*16 + (t>>4), cols (t&15)*4.
// ---------------------------------------------------------------------------
__global__ __launch_bounds__(256) void attn_combine(
    const bf16_t* __restrict__ opart, const float* __restrict__ ml,
    float* __restrict__ out) {
  const int bid = blockIdx.x;
  const int cid = bid >> 2;           // (b<<5)|qi
  const int rq  = bid & 3;
  const int b   = cid >> 5;
  const int qi  = cid & 31;
  const int row = rq * 16 + (threadIdx.x >> 4);
  const int c4  = (threadIdx.x & 15) * 4;

  float o0 = 0.f, o1 = 0.f, o2 = 0.f, o3 = 0.f;
  float M = -1e30f, L = 0.f;
#pragma unroll
  for (int s = 0; s < 4; ++s) {
    const size_t prow = (size_t)(cid * 4 + s) * 64 + row;
    float ms = ml[prow * 2 + 0];
    float ls = ml[prow * 2 + 1];
    float Mn = fmaxf(M, ms);
    float a  = exp2f(M - Mn);
    float bs = exp2f(ms - Mn);
    bf16x4 ov = *(const bf16x4*)(opart + prow * 64 + c4);
    o0 = o0 * a + (float)ov[0] * bs;
    o1 = o1 * a + (float)ov[1] * bs;
    o2 = o2 * a + (float)ov[2] * bs;
    o3 = o3 * a + (float)ov[3] * bs;
    L = L * a + ls * bs;
    M = Mn;
  }
  float inv = 1.0f / L;
  float4 v = {o0 * inv, o1 * inv, o2 * inv, o3 * inv};
  *(float4*)(out + ((size_t)b * T_ + qi * 64 + row) * H_ + c4) = v;
}

// ---------------------------------------------------------------------------
extern "C" void kernel_launch(void* const* d_in, const int* in_sizes, int n_in,
                              void* d_out, int out_size, void* d_ws, size_t ws_size,
                              hipStream_t stream) {
  const float* x  = (const float*)d_in[0];
  const float* Wq = (const float*)d_in[1];
  const float* Wk = (const float*)d_in[2];
  const float* Wv = (const float*)d_in[3];

  char* ws = (char*)d_ws;
  bf16_t* Wt    = (bf16_t*)(ws);                     // 384 KB
  bf16_t* qb    = (bf16_t*)(ws + (1u << 20));        // 2 MB (q * QSCALE)
  bf16_t* kb2   = (bf16_t*)(ws + 3u * (1u << 20));   // 2 MB (frag-tile order)
  bf16_t* vt2   = (bf16_t*)(ws + 5u * (1u << 20));   // 2 MB (frag-tile order)
  bf16_t* opart = (bf16_t*)(ws + 8u * (1u << 20));   // 8 MB (1024*64*64 bf16)
  float*  mlbuf = (float*)(ws + 17u * (1u << 20));   // 512 KB
  float*  outp  = (float*)d_out;

  hipLaunchKernelGGL(wprep_kernel, dim3(48), dim3(256), 0, stream, Wq, Wk, Wv, Wt);
  hipLaunchKernelGGL(qkv_kernel, dim3(512), dim3(256), 0, stream, x, Wt, qb, kb2, vt2);
  hipLaunchKernelGGL(attn_partial, dim3(1024), dim3(256), 0, stream, qb, kb2, vt2, opart, mlbuf);
  hipLaunchKernelGGL(attn_combine, dim3(1024), dim3(256), 0, stream, opart, mlbuf, outp);
}